// Round 2
// baseline (609.223 us; speedup 1.0000x reference)
//
#include <hip/hip_runtime.h>
#include <hip/hip_bf16.h>
#include <cstdint>

#define TB 256
#define SCAN_T 256
#define SCAN_C 2048

__device__ __forceinline__ float lrelu_exp(float e){
  e = e > 0.0f ? e : 0.2f * e;
  return __expf(e);
}

// ---------------- CSR build (dst-indexed) ----------------
__global__ __launch_bounds__(TB) void k_hist(const int* __restrict__ ei, int E, int n, int* __restrict__ deg){
  int e = blockIdx.x * TB + threadIdx.x;
  if (e >= E) return;
  int d = ei[E + e];
  if ((unsigned)d < (unsigned)n) atomicAdd(&deg[d], 1);
}

__global__ __launch_bounds__(SCAN_T) void k_scan1(const int* __restrict__ deg, int n,
                                                  int* __restrict__ excl, int* __restrict__ partials){
  __shared__ int sums[SCAN_T];
  int t = threadIdx.x;
  int base = blockIdx.x * SCAN_C + t * 8;
  int v[8]; int s = 0;
  #pragma unroll
  for (int i = 0; i < 8; ++i){ int idx = base + i; v[i] = (idx < n) ? deg[idx] : 0; s += v[i]; }
  sums[t] = s;
  __syncthreads();
  for (int off = 1; off < SCAN_T; off <<= 1){
    int add = (t >= off) ? sums[t - off] : 0;
    __syncthreads();
    sums[t] += add;
    __syncthreads();
  }
  int run = sums[t] - s;                       // exclusive within chunk
  if (t == SCAN_T - 1) partials[blockIdx.x] = sums[t];
  #pragma unroll
  for (int i = 0; i < 8; ++i){ int idx = base + i; if (idx < n) excl[idx] = run; run += v[i]; }
}

__global__ void k_scan2(int* partials, int nb){
  int lane = threadIdx.x;                      // 64 threads, nb <= 64
  int orig = (lane < nb) ? partials[lane] : 0;
  int v = orig;
  for (int off = 1; off < 64; off <<= 1){
    int u = __shfl_up(v, off);
    if (lane >= off) v += u;
  }
  if (lane < nb) partials[lane] = v - orig;    // exclusive
}

__global__ __launch_bounds__(TB) void k_scan3(int* __restrict__ excl, int n, const int* __restrict__ partials){
  int i = blockIdx.x * TB + threadIdx.x;
  if (i < n) excl[i] += partials[i / SCAN_C];
}

__global__ __launch_bounds__(TB) void k_scatter(const int* __restrict__ ei, int E, int n,
                                                int* __restrict__ cursor, int* __restrict__ col){
  int e = blockIdx.x * TB + threadIdx.x;
  if (e >= E) return;
  int s = ei[e];
  int d = ei[E + e];
  if ((unsigned)d >= (unsigned)n || (unsigned)s >= (unsigned)n) return;
  int pos = atomicAdd(&cursor[d], 1);
  col[pos] = s;
}

// ---------------- GEMM1: h1[N,128] = x[N,128] @ W1[128,128] ----------------
__global__ __launch_bounds__(256) void k_gemm1(const float* __restrict__ x, const float* __restrict__ W,
                                               float* __restrict__ h, int n){
  __shared__ float xs[32][128];   // [k][node]
  __shared__ float ws[32][128];   // [k][col]
  int t = threadIdx.x;
  int ng = t & 15, cg = t >> 4;   // nodes ng+16*i, cols cg*8..+8
  int node0 = blockIdx.x * 128;
  int nodeL = t >> 1, kh = t & 1; // loader mapping
  float acc[8][8];
  #pragma unroll
  for (int i = 0; i < 8; ++i)
    #pragma unroll
    for (int j = 0; j < 8; ++j) acc[i][j] = 0.0f;

  for (int kc = 0; kc < 4; ++kc){
    int k0 = kc * 32;
    __syncthreads();
    {
      int gn = node0 + nodeL;
      const float4* src = (const float4*)(x + (size_t)gn * 128 + k0 + kh * 16);
      #pragma unroll
      for (int u = 0; u < 4; ++u){
        float4 f = (gn < n) ? src[u] : make_float4(0.f, 0.f, 0.f, 0.f);
        int kk = kh * 16 + u * 4;
        xs[kk + 0][nodeL] = f.x; xs[kk + 1][nodeL] = f.y;
        xs[kk + 2][nodeL] = f.z; xs[kk + 3][nodeL] = f.w;
      }
      const float4* wsrc = (const float4*)(W + (size_t)k0 * 128);
      float4* wdst = (float4*)(&ws[0][0]);
      #pragma unroll
      for (int u = 0; u < 4; ++u) wdst[t + 256 * u] = wsrc[t + 256 * u];
    }
    __syncthreads();
    #pragma unroll 8
    for (int k = 0; k < 32; ++k){
      float xv[8];
      #pragma unroll
      for (int i = 0; i < 8; ++i) xv[i] = xs[k][ng + 16 * i];
      float4 w0 = *(const float4*)&ws[k][cg * 8];
      float4 w1 = *(const float4*)&ws[k][cg * 8 + 4];
      float wv[8] = {w0.x, w0.y, w0.z, w0.w, w1.x, w1.y, w1.z, w1.w};
      #pragma unroll
      for (int i = 0; i < 8; ++i)
        #pragma unroll
        for (int j = 0; j < 8; ++j) acc[i][j] = fmaf(xv[i], wv[j], acc[i][j]);
    }
  }
  #pragma unroll
  for (int i = 0; i < 8; ++i){
    int gn = node0 + ng + 16 * i;
    if (gn < n){
      float4 o0 = make_float4(acc[i][0], acc[i][1], acc[i][2], acc[i][3]);
      float4 o1 = make_float4(acc[i][4], acc[i][5], acc[i][6], acc[i][7]);
      *(float4*)(h + (size_t)gn * 128 + cg * 8)     = o0;
      *(float4*)(h + (size_t)gn * 128 + cg * 8 + 4) = o1;
    }
  }
}

// ---------------- att1: a_s/a_d [N,8] from h1 ----------------
__global__ __launch_bounds__(TB) void k_att1(const float* __restrict__ h1, const float* __restrict__ asw,
                                             const float* __restrict__ adw,
                                             float* __restrict__ a_s, float* __restrict__ a_d, int n8){
  int idx = blockIdx.x * TB + threadIdx.x;   // node*8 + h
  if (idx >= n8) return;
  int h = idx & 7;
  const float4* hv = (const float4*)(h1 + (size_t)idx * 16);
  const float4* sv = (const float4*)(asw + h * 16);
  const float4* dv = (const float4*)(adw + h * 16);
  float ss = 0.f, dd = 0.f;
  #pragma unroll
  for (int u = 0; u < 4; ++u){
    float4 hh = hv[u], s4 = sv[u], d4 = dv[u];
    ss += hh.x * s4.x + hh.y * s4.y + hh.z * s4.z + hh.w * s4.w;
    dd += hh.x * d4.x + hh.y * d4.y + hh.z * d4.z + hh.w * d4.w;
  }
  a_s[idx] = ss; a_d[idx] = dd;
}

// ---------------- agg1: out1 = relu(softmax-agg(h1) + b1) ----------------
__global__ __launch_bounds__(TB) void k_agg1(const float* __restrict__ h1, const float* __restrict__ a_s,
    const float* __restrict__ a_d, const int* __restrict__ col, const int* __restrict__ cursor,
    const int* __restrict__ deg, const float* __restrict__ b1, float* __restrict__ out1, int n){
  int lt = threadIdx.x & 127;
  int node = blockIdx.x * 2 + (threadIdx.x >> 7);
  if (node >= n) return;
  int h = lt >> 4;
  float adn = a_d[(size_t)node * 8 + h];
  float w = lrelu_exp(a_s[(size_t)node * 8 + h] + adn);   // self-loop
  float acc = w * h1[(size_t)node * 128 + lt];
  float denom = w;
  int end = cursor[node];
  int pp = end - deg[node];
  for (; pp + 2 <= end; pp += 2){
    int s0 = col[pp], s1 = col[pp + 1];
    float w0 = lrelu_exp(a_s[(size_t)s0 * 8 + h] + adn);
    float w1 = lrelu_exp(a_s[(size_t)s1 * 8 + h] + adn);
    float v0 = h1[(size_t)s0 * 128 + lt];
    float v1 = h1[(size_t)s1 * 128 + lt];
    acc = fmaf(w0, v0, acc);
    acc = fmaf(w1, v1, acc);
    denom += w0 + w1;
  }
  if (pp < end){
    int s0 = col[pp];
    float w0 = lrelu_exp(a_s[(size_t)s0 * 8 + h] + adn);
    acc = fmaf(w0, h1[(size_t)s0 * 128 + lt], acc);
    denom += w0;
  }
  float o = acc / denom + b1[lt];
  out1[(size_t)node * 128 + lt] = o > 0.0f ? o : 0.0f;
}

// ---------------- GEMM2: h2[N,40] = out1[N,128] @ W2[128,40] ----------------
__global__ __launch_bounds__(256) void k_gemm2(const float* __restrict__ a, const float* __restrict__ W2,
                                               float* __restrict__ h2, int n){
  __shared__ float xs[32][256];   // [k][node] 32KB
  __shared__ float ws[128][40];   // 20KB
  int t = threadIdx.x;
  for (int i = t; i < 128 * 40; i += 256) (&ws[0][0])[i] = W2[i];
  int ng = t & 63, cg = t >> 6;   // nodes ng+64*i, cols cg*10..+10 (cg uniform per wave)
  int node0 = blockIdx.x * 256;
  int nodeL = t >> 1, kh = t & 1;
  float acc[4][10];
  #pragma unroll
  for (int i = 0; i < 4; ++i)
    #pragma unroll
    for (int j = 0; j < 10; ++j) acc[i][j] = 0.0f;

  for (int kc = 0; kc < 4; ++kc){
    int k0 = kc * 32;
    __syncthreads();
    #pragma unroll
    for (int nn = 0; nn < 2; ++nn){
      int ln = nodeL + nn * 128;
      int gn = node0 + ln;
      const float4* src = (const float4*)(a + (size_t)gn * 128 + k0 + kh * 16);
      #pragma unroll
      for (int u = 0; u < 4; ++u){
        float4 f = (gn < n) ? src[u] : make_float4(0.f, 0.f, 0.f, 0.f);
        int kk = kh * 16 + u * 4;
        xs[kk + 0][ln] = f.x; xs[kk + 1][ln] = f.y;
        xs[kk + 2][ln] = f.z; xs[kk + 3][ln] = f.w;
      }
    }
    __syncthreads();
    #pragma unroll 4
    for (int k = 0; k < 32; ++k){
      float xv[4];
      #pragma unroll
      for (int i = 0; i < 4; ++i) xv[i] = xs[k][ng + 64 * i];
      float wv[10];
      #pragma unroll
      for (int j = 0; j < 10; ++j) wv[j] = ws[k0 + k][cg * 10 + j];
      #pragma unroll
      for (int i = 0; i < 4; ++i)
        #pragma unroll
        for (int j = 0; j < 10; ++j) acc[i][j] = fmaf(xv[i], wv[j], acc[i][j]);
    }
  }
  #pragma unroll
  for (int i = 0; i < 4; ++i){
    int gn = node0 + ng + 64 * i;
    if (gn < n){
      #pragma unroll
      for (int j = 0; j < 5; ++j){
        float2 o = make_float2(acc[i][2 * j], acc[i][2 * j + 1]);
        *(float2*)(h2 + (size_t)gn * 40 + cg * 10 + 2 * j) = o;
      }
    }
  }
}

// ---------------- att2: a_s/a_d [N] from h2 ----------------
__global__ __launch_bounds__(TB) void k_att2(const float* __restrict__ h2, const float* __restrict__ asw,
                                             const float* __restrict__ adw,
                                             float* __restrict__ a_s, float* __restrict__ a_d, int n){
  int t = threadIdx.x;
  int node = blockIdx.x * 32 + (t >> 3);
  int sub = t & 7;
  if (node >= n) return;
  float ss = 0.f, dd = 0.f;
  for (int j = sub; j < 40; j += 8){
    float v = h2[(size_t)node * 40 + j];
    ss += v * asw[j];
    dd += v * adw[j];
  }
  #pragma unroll
  for (int off = 1; off < 8; off <<= 1){
    ss += __shfl_xor(ss, off);
    dd += __shfl_xor(dd, off);
  }
  if (sub == 0){ a_s[node] = ss; a_d[node] = dd; }
}

// ---------------- agg2 + log_softmax -> out ----------------
__global__ __launch_bounds__(TB) void k_agg2(const float* __restrict__ h2, const float* __restrict__ a_s,
    const float* __restrict__ a_d, const int* __restrict__ col, const int* __restrict__ cursor,
    const int* __restrict__ deg, const float* __restrict__ b2, float* __restrict__ out, int n){
  int lane = threadIdx.x & 63;
  int node = blockIdx.x * 4 + (threadIdx.x >> 6);
  if (node >= n) return;
  bool act = lane < 40;
  float adn = a_d[node];
  float w = lrelu_exp(a_s[node] + adn);       // self-loop
  float hval = act ? h2[(size_t)node * 40 + lane] : 0.0f;
  float acc = w * hval, denom = w;
  int end = cursor[node];
  int pp = end - deg[node];
  for (; pp + 2 <= end; pp += 2){
    int s0 = col[pp], s1 = col[pp + 1];
    float w0 = lrelu_exp(a_s[s0] + adn);
    float w1 = lrelu_exp(a_s[s1] + adn);
    float v0 = act ? h2[(size_t)s0 * 40 + lane] : 0.0f;
    float v1 = act ? h2[(size_t)s1 * 40 + lane] : 0.0f;
    acc = fmaf(w0, v0, acc);
    acc = fmaf(w1, v1, acc);
    denom += w0 + w1;
  }
  if (pp < end){
    int s0 = col[pp];
    float w0 = lrelu_exp(a_s[s0] + adn);
    acc = fmaf(w0, act ? h2[(size_t)s0 * 40 + lane] : 0.0f, acc);
    denom += w0;
  }
  float v = act ? (acc / denom + b2[lane]) : -1e30f;
  float m = v;
  #pragma unroll
  for (int off = 32; off >= 1; off >>= 1) m = fmaxf(m, __shfl_xor(m, off));
  float ex = act ? __expf(v - m) : 0.0f;
  float S = ex;
  #pragma unroll
  for (int off = 32; off >= 1; off >>= 1) S += __shfl_xor(S, off);
  if (act) out[(size_t)node * 40 + lane] = v - m - __logf(S);
}

extern "C" void kernel_launch(void* const* d_in, const int* in_sizes, int n_in,
                              void* d_out, int out_size, void* d_ws, size_t ws_size,
                              hipStream_t stream){
  const float* x    = (const float*)d_in[0];
  const int*   ei   = (const int*)d_in[1];          // int32 (jax x64 disabled)
  const float* W1   = (const float*)d_in[2];
  const float* as1w = (const float*)d_in[3];
  const float* ad1w = (const float*)d_in[4];
  const float* b1   = (const float*)d_in[5];
  const float* W2   = (const float*)d_in[6];
  const float* as2w = (const float*)d_in[7];
  const float* ad2w = (const float*)d_in[8];
  const float* b2   = (const float*)d_in[9];
  float* out = (float*)d_out;
  const int N = in_sizes[0] / 128;
  const int E = in_sizes[1] / 2;

  char* p = (char*)d_ws;
  auto alloc = [&](size_t bytes) -> void* {
    void* r = (void*)p;
    p += (bytes + 511) & ~(size_t)511;
    return r;
  };
  int*   deg      = (int*)  alloc((size_t)N * 4);
  int*   cursor   = (int*)  alloc((size_t)N * 4);
  int*   partials = (int*)  alloc(64 * 4);
  int*   col      = (int*)  alloc((size_t)E * 4);
  float* a_s1     = (float*)alloc((size_t)N * 8 * 4);
  float* a_d1     = (float*)alloc((size_t)N * 8 * 4);
  float* out1     = (float*)alloc((size_t)N * 128 * 4);
  float* h1       = (float*)alloc((size_t)N * 128 * 4);
  // layer-2 temporaries overlay h1 (h1 is dead after agg1)
  float* h2   = h1;                       // N*40
  float* a_s2 = h1 + (size_t)N * 40;      // N
  float* a_d2 = a_s2 + N;                 // N

  hipMemsetAsync(deg, 0, (size_t)N * 4, stream);

  int gE = (E + TB - 1) / TB;
  int nchunk = (N + SCAN_C - 1) / SCAN_C;

  k_hist   <<<gE, TB, 0, stream>>>(ei, E, N, deg);
  k_scan1  <<<nchunk, SCAN_T, 0, stream>>>(deg, N, cursor, partials);
  k_scan2  <<<1, 64, 0, stream>>>(partials, nchunk);
  k_scan3  <<<(N + TB - 1) / TB, TB, 0, stream>>>(cursor, N, partials);
  k_scatter<<<gE, TB, 0, stream>>>(ei, E, N, cursor, col);

  k_gemm1  <<<(N + 127) / 128, 256, 0, stream>>>(x, W1, h1, N);
  k_att1   <<<(N * 8 + TB - 1) / TB, TB, 0, stream>>>(h1, as1w, ad1w, a_s1, a_d1, N * 8);
  k_agg1   <<<(N + 1) / 2, TB, 0, stream>>>(h1, a_s1, a_d1, col, cursor, deg, b1, out1, N);

  k_gemm2  <<<(N + 255) / 256, 256, 0, stream>>>(out1, W2, h2, N);
  k_att2   <<<(N + 31) / 32, TB, 0, stream>>>(h2, as2w, ad2w, a_s2, a_d2, N);
  k_agg2   <<<(N + 3) / 4, TB, 0, stream>>>(h2, a_s2, a_d2, col, cursor, deg, b2, out, N);
}

// Round 3
// 567.369 us; speedup vs baseline: 1.0738x; 1.0738x over previous
//
#include <hip/hip_runtime.h>
#include <hip/hip_bf16.h>
#include <cstdint>

#define TB 256
#define SCAN_T 256
#define SCAN_C 2048

__device__ __forceinline__ float lrelu_exp(float e){
  e = e > 0.0f ? e : 0.2f * e;
  return __expf(e);
}
__device__ __forceinline__ unsigned short f2bf(float f){
  unsigned u = __float_as_uint(f);
  u = (u + 0x7fffu + ((u >> 16) & 1u)) >> 16;   // RNE
  return (unsigned short)u;
}
__device__ __forceinline__ float bf2f(unsigned short s){
  return __uint_as_float(((unsigned)s) << 16);
}
__device__ __forceinline__ unsigned pack2(float a, float b){
  return (unsigned)f2bf(a) | ((unsigned)f2bf(b) << 16);
}

// ---------------- CSR build (dst-indexed) ----------------
__global__ __launch_bounds__(TB) void k_hist(const int* __restrict__ ei, int E, int n, int* __restrict__ deg){
  int e = blockIdx.x * TB + threadIdx.x;
  if (e >= E) return;
  int d = ei[E + e];
  if ((unsigned)d < (unsigned)n) atomicAdd(&deg[d], 1);
}

__global__ __launch_bounds__(SCAN_T) void k_scan1(const int* __restrict__ deg, int n,
                                                  int* __restrict__ excl, int* __restrict__ partials){
  __shared__ int sums[SCAN_T];
  int t = threadIdx.x;
  int base = blockIdx.x * SCAN_C + t * 8;
  int v[8]; int s = 0;
  #pragma unroll
  for (int i = 0; i < 8; ++i){ int idx = base + i; v[i] = (idx < n) ? deg[idx] : 0; s += v[i]; }
  sums[t] = s;
  __syncthreads();
  for (int off = 1; off < SCAN_T; off <<= 1){
    int add = (t >= off) ? sums[t - off] : 0;
    __syncthreads();
    sums[t] += add;
    __syncthreads();
  }
  int run = sums[t] - s;
  if (t == SCAN_T - 1) partials[blockIdx.x] = sums[t];
  #pragma unroll
  for (int i = 0; i < 8; ++i){ int idx = base + i; if (idx < n) excl[idx] = run; run += v[i]; }
}

__global__ void k_scan2(int* partials, int nb){
  int lane = threadIdx.x;
  int orig = (lane < nb) ? partials[lane] : 0;
  int v = orig;
  for (int off = 1; off < 64; off <<= 1){
    int u = __shfl_up(v, off);
    if (lane >= off) v += u;
  }
  if (lane < nb) partials[lane] = v - orig;
}

__global__ __launch_bounds__(TB) void k_scan3(int* __restrict__ excl, int n, const int* __restrict__ partials){
  int i = blockIdx.x * TB + threadIdx.x;
  if (i < n) excl[i] += partials[i / SCAN_C];
}

__global__ __launch_bounds__(TB) void k_scatter(const int* __restrict__ ei, int E, int n,
                                                int* __restrict__ cursor, int* __restrict__ col,
                                                int* __restrict__ dstv){
  int e = blockIdx.x * TB + threadIdx.x;
  if (e >= E) return;
  int s = ei[e];
  int d = ei[E + e];
  if ((unsigned)d >= (unsigned)n || (unsigned)s >= (unsigned)n) return;
  int pos = atomicAdd(&cursor[d], 1);
  col[pos] = s;
  dstv[pos] = d;
}

// ---------------- GEMM1: h1b[N,128](bf16) = x[N,128] @ W1[128,128] ----------------
__global__ __launch_bounds__(256) void k_gemm1(const float* __restrict__ x, const float* __restrict__ W,
                                               unsigned short* __restrict__ hb, int n){
  __shared__ float xs[32][128];
  __shared__ float ws[32][128];
  int t = threadIdx.x;
  int ng = t & 15, cg = t >> 4;
  int node0 = blockIdx.x * 128;
  int nodeL = t >> 1, kh = t & 1;
  float acc[8][8];
  #pragma unroll
  for (int i = 0; i < 8; ++i)
    #pragma unroll
    for (int j = 0; j < 8; ++j) acc[i][j] = 0.0f;

  for (int kc = 0; kc < 4; ++kc){
    int k0 = kc * 32;
    __syncthreads();
    {
      int gn = node0 + nodeL;
      const float4* src = (const float4*)(x + (size_t)gn * 128 + k0 + kh * 16);
      #pragma unroll
      for (int u = 0; u < 4; ++u){
        float4 f = (gn < n) ? src[u] : make_float4(0.f, 0.f, 0.f, 0.f);
        int kk = kh * 16 + u * 4;
        xs[kk + 0][nodeL] = f.x; xs[kk + 1][nodeL] = f.y;
        xs[kk + 2][nodeL] = f.z; xs[kk + 3][nodeL] = f.w;
      }
      const float4* wsrc = (const float4*)(W + (size_t)k0 * 128);
      float4* wdst = (float4*)(&ws[0][0]);
      #pragma unroll
      for (int u = 0; u < 4; ++u) wdst[t + 256 * u] = wsrc[t + 256 * u];
    }
    __syncthreads();
    #pragma unroll 8
    for (int k = 0; k < 32; ++k){
      float xv[8];
      #pragma unroll
      for (int i = 0; i < 8; ++i) xv[i] = xs[k][ng + 16 * i];
      float4 w0 = *(const float4*)&ws[k][cg * 8];
      float4 w1 = *(const float4*)&ws[k][cg * 8 + 4];
      float wv[8] = {w0.x, w0.y, w0.z, w0.w, w1.x, w1.y, w1.z, w1.w};
      #pragma unroll
      for (int i = 0; i < 8; ++i)
        #pragma unroll
        for (int j = 0; j < 8; ++j) acc[i][j] = fmaf(xv[i], wv[j], acc[i][j]);
    }
  }
  #pragma unroll
  for (int i = 0; i < 8; ++i){
    int gn = node0 + ng + 16 * i;
    if (gn < n){
      uint4 o;
      o.x = pack2(acc[i][0], acc[i][1]);
      o.y = pack2(acc[i][2], acc[i][3]);
      o.z = pack2(acc[i][4], acc[i][5]);
      o.w = pack2(acc[i][6], acc[i][7]);
      *(uint4*)(hb + (size_t)gn * 128 + cg * 8) = o;
    }
  }
}

// ---------------- att1: a_s/a_d [N,8] from h1b ----------------
__global__ __launch_bounds__(TB) void k_att1(const unsigned short* __restrict__ hb, const float* __restrict__ asw,
                                             const float* __restrict__ adw,
                                             float* __restrict__ a_s, float* __restrict__ a_d, int n8){
  int idx = blockIdx.x * TB + threadIdx.x;   // node*8 + h
  if (idx >= n8) return;
  int h = idx & 7;
  uint4 lo = *(const uint4*)(hb + (size_t)idx * 16);
  uint4 hi = *(const uint4*)(hb + (size_t)idx * 16 + 8);
  float v[16];
  unsigned w_[8] = {lo.x, lo.y, lo.z, lo.w, hi.x, hi.y, hi.z, hi.w};
  #pragma unroll
  for (int u = 0; u < 8; ++u){
    v[2 * u]     = __uint_as_float(w_[u] << 16);
    v[2 * u + 1] = __uint_as_float(w_[u] & 0xffff0000u);
  }
  float ss = 0.f, dd = 0.f;
  #pragma unroll
  for (int u = 0; u < 16; ++u){
    ss = fmaf(v[u], asw[h * 16 + u], ss);
    dd = fmaf(v[u], adw[h * 16 + u], dd);
  }
  a_s[idx] = ss; a_d[idx] = dd;
}

// ---------------- weights1: w1w[pos][8] (bf16) ----------------
__global__ __launch_bounds__(TB) void k_weights1(const int* __restrict__ col, const int* __restrict__ dstv,
                                                 const float* __restrict__ a_s, const float* __restrict__ a_d,
                                                 unsigned short* __restrict__ w1w, int E){
  int pos = blockIdx.x * TB + threadIdx.x;
  if (pos >= E) return;
  int s = col[pos], d = dstv[pos];
  float4 as0 = *(const float4*)(a_s + (size_t)s * 8);
  float4 as1 = *(const float4*)(a_s + (size_t)s * 8 + 4);
  float4 ad0 = *(const float4*)(a_d + (size_t)d * 8);
  float4 ad1 = *(const float4*)(a_d + (size_t)d * 8 + 4);
  uint4 o;
  o.x = pack2(lrelu_exp(as0.x + ad0.x), lrelu_exp(as0.y + ad0.y));
  o.y = pack2(lrelu_exp(as0.z + ad0.z), lrelu_exp(as0.w + ad0.w));
  o.z = pack2(lrelu_exp(as1.x + ad1.x), lrelu_exp(as1.y + ad1.y));
  o.w = pack2(lrelu_exp(as1.z + ad1.z), lrelu_exp(as1.w + ad1.w));
  *(uint4*)(w1w + (size_t)pos * 8) = o;
}

// ---------------- agg1: out1 = relu(softmax-agg(h1b) + b1) ----------------
__global__ __launch_bounds__(TB) void k_agg1(const unsigned short* __restrict__ hb, const float* __restrict__ a_s,
    const float* __restrict__ a_d, const int* __restrict__ col, const unsigned short* __restrict__ w1w,
    const int* __restrict__ cursor, const int* __restrict__ deg,
    const float* __restrict__ b1, float* __restrict__ out1, int n){
  int lt = threadIdx.x & 127;
  int node = blockIdx.x * 2 + (threadIdx.x >> 7);
  if (node >= n) return;
  int h = lt >> 4;
  float w = lrelu_exp(a_s[(size_t)node * 8 + h] + a_d[(size_t)node * 8 + h]);   // self-loop
  float acc = w * bf2f(hb[(size_t)node * 128 + lt]);
  float denom = w;
  int end = cursor[node];
  int pp = end - deg[node];
  for (; pp + 4 <= end; pp += 4){
    int s0 = col[pp], s1 = col[pp + 1], s2 = col[pp + 2], s3 = col[pp + 3];
    float w0 = bf2f(w1w[(size_t)(pp    ) * 8 + h]);
    float w1 = bf2f(w1w[(size_t)(pp + 1) * 8 + h]);
    float w2 = bf2f(w1w[(size_t)(pp + 2) * 8 + h]);
    float w3 = bf2f(w1w[(size_t)(pp + 3) * 8 + h]);
    float v0 = bf2f(hb[(size_t)s0 * 128 + lt]);
    float v1 = bf2f(hb[(size_t)s1 * 128 + lt]);
    float v2 = bf2f(hb[(size_t)s2 * 128 + lt]);
    float v3 = bf2f(hb[(size_t)s3 * 128 + lt]);
    acc = fmaf(w0, v0, acc); acc = fmaf(w1, v1, acc);
    acc = fmaf(w2, v2, acc); acc = fmaf(w3, v3, acc);
    denom += (w0 + w1) + (w2 + w3);
  }
  for (; pp < end; ++pp){
    int s0 = col[pp];
    float w0 = bf2f(w1w[(size_t)pp * 8 + h]);
    acc = fmaf(w0, bf2f(hb[(size_t)s0 * 128 + lt]), acc);
    denom += w0;
  }
  float o = acc / denom + b1[lt];
  out1[(size_t)node * 128 + lt] = o > 0.0f ? o : 0.0f;
}

// ---------------- GEMM2: h2b[N,40](bf16) = out1[N,128] @ W2[128,40] ----------------
__global__ __launch_bounds__(256) void k_gemm2(const float* __restrict__ a, const float* __restrict__ W2,
                                               unsigned short* __restrict__ h2b, int n){
  __shared__ float xs[32][256];
  __shared__ float ws[128][40];
  int t = threadIdx.x;
  for (int i = t; i < 128 * 40; i += 256) (&ws[0][0])[i] = W2[i];
  int ng = t & 63, cg = t >> 6;
  int node0 = blockIdx.x * 256;
  int nodeL = t >> 1, kh = t & 1;
  float acc[4][10];
  #pragma unroll
  for (int i = 0; i < 4; ++i)
    #pragma unroll
    for (int j = 0; j < 10; ++j) acc[i][j] = 0.0f;

  for (int kc = 0; kc < 4; ++kc){
    int k0 = kc * 32;
    __syncthreads();
    #pragma unroll
    for (int nn = 0; nn < 2; ++nn){
      int ln = nodeL + nn * 128;
      int gn = node0 + ln;
      const float4* src = (const float4*)(a + (size_t)gn * 128 + k0 + kh * 16);
      #pragma unroll
      for (int u = 0; u < 4; ++u){
        float4 f = (gn < n) ? src[u] : make_float4(0.f, 0.f, 0.f, 0.f);
        int kk = kh * 16 + u * 4;
        xs[kk + 0][ln] = f.x; xs[kk + 1][ln] = f.y;
        xs[kk + 2][ln] = f.z; xs[kk + 3][ln] = f.w;
      }
    }
    __syncthreads();
    #pragma unroll 4
    for (int k = 0; k < 32; ++k){
      float xv[4];
      #pragma unroll
      for (int i = 0; i < 4; ++i) xv[i] = xs[k][ng + 64 * i];
      float wv[10];
      #pragma unroll
      for (int j = 0; j < 10; ++j) wv[j] = ws[k0 + k][cg * 10 + j];
      #pragma unroll
      for (int i = 0; i < 4; ++i)
        #pragma unroll
        for (int j = 0; j < 10; ++j) acc[i][j] = fmaf(xv[i], wv[j], acc[i][j]);
    }
  }
  #pragma unroll
  for (int i = 0; i < 4; ++i){
    int gn = node0 + ng + 64 * i;
    if (gn < n){
      unsigned pk[5];
      #pragma unroll
      for (int j = 0; j < 5; ++j) pk[j] = pack2(acc[i][2 * j], acc[i][2 * j + 1]);
      unsigned* dst = (unsigned*)(h2b + (size_t)gn * 40 + cg * 10);
      #pragma unroll
      for (int j = 0; j < 5; ++j) dst[j] = pk[j];
    }
  }
}

// ---------------- att2: a_s/a_d [N] from h2b ----------------
__global__ __launch_bounds__(TB) void k_att2(const unsigned short* __restrict__ h2b, const float* __restrict__ asw,
                                             const float* __restrict__ adw,
                                             float* __restrict__ a_s, float* __restrict__ a_d, int n){
  int t = threadIdx.x;
  int node = blockIdx.x * 32 + (t >> 3);
  int sub = t & 7;
  if (node >= n) return;
  float ss = 0.f, dd = 0.f;
  for (int j = sub; j < 40; j += 8){
    float v = bf2f(h2b[(size_t)node * 40 + j]);
    ss = fmaf(v, asw[j], ss);
    dd = fmaf(v, adw[j], dd);
  }
  #pragma unroll
  for (int off = 1; off < 8; off <<= 1){
    ss += __shfl_xor(ss, off);
    dd += __shfl_xor(dd, off);
  }
  if (sub == 0){ a_s[node] = ss; a_d[node] = dd; }
}

// ---------------- weights2: w2w[pos] (bf16) ----------------
__global__ __launch_bounds__(TB) void k_weights2(const int* __restrict__ col, const int* __restrict__ dstv,
                                                 const float* __restrict__ a_s, const float* __restrict__ a_d,
                                                 unsigned short* __restrict__ w2w, int E){
  int pos = blockIdx.x * TB + threadIdx.x;
  if (pos >= E) return;
  w2w[pos] = f2bf(lrelu_exp(a_s[col[pos]] + a_d[dstv[pos]]));
}

// ---------------- agg2 + log_softmax -> out ----------------
__global__ __launch_bounds__(TB) void k_agg2(const unsigned short* __restrict__ h2b, const float* __restrict__ a_s,
    const float* __restrict__ a_d, const int* __restrict__ col, const unsigned short* __restrict__ w2w,
    const int* __restrict__ cursor, const int* __restrict__ deg,
    const float* __restrict__ b2, float* __restrict__ out, int n){
  int lane = threadIdx.x & 63;
  int node = blockIdx.x * 4 + (threadIdx.x >> 6);
  if (node >= n) return;
  bool act = lane < 40;
  float w = lrelu_exp(a_s[node] + a_d[node]);       // self-loop
  float acc = w * (act ? bf2f(h2b[(size_t)node * 40 + lane]) : 0.0f);
  float denom = w;
  int end = cursor[node];
  int pp = end - deg[node];
  for (; pp + 4 <= end; pp += 4){
    int s0 = col[pp], s1 = col[pp + 1], s2 = col[pp + 2], s3 = col[pp + 3];
    float w0 = bf2f(w2w[pp]), w1 = bf2f(w2w[pp + 1]);
    float w2 = bf2f(w2w[pp + 2]), w3 = bf2f(w2w[pp + 3]);
    float v0 = act ? bf2f(h2b[(size_t)s0 * 40 + lane]) : 0.0f;
    float v1 = act ? bf2f(h2b[(size_t)s1 * 40 + lane]) : 0.0f;
    float v2 = act ? bf2f(h2b[(size_t)s2 * 40 + lane]) : 0.0f;
    float v3 = act ? bf2f(h2b[(size_t)s3 * 40 + lane]) : 0.0f;
    acc = fmaf(w0, v0, acc); acc = fmaf(w1, v1, acc);
    acc = fmaf(w2, v2, acc); acc = fmaf(w3, v3, acc);
    denom += (w0 + w1) + (w2 + w3);
  }
  for (; pp < end; ++pp){
    float w0 = bf2f(w2w[pp]);
    acc = fmaf(w0, act ? bf2f(h2b[(size_t)col[pp] * 40 + lane]) : 0.0f, acc);
    denom += w0;
  }
  float v = act ? (acc / denom + b2[lane]) : -1e30f;
  float m = v;
  #pragma unroll
  for (int off = 32; off >= 1; off >>= 1) m = fmaxf(m, __shfl_xor(m, off));
  float ex = act ? __expf(v - m) : 0.0f;
  float S = ex;
  #pragma unroll
  for (int off = 32; off >= 1; off >>= 1) S += __shfl_xor(S, off);
  if (act) out[(size_t)node * 40 + lane] = v - m - __logf(S);
}

extern "C" void kernel_launch(void* const* d_in, const int* in_sizes, int n_in,
                              void* d_out, int out_size, void* d_ws, size_t ws_size,
                              hipStream_t stream){
  const float* x    = (const float*)d_in[0];
  const int*   ei   = (const int*)d_in[1];          // int32 (jax x64 disabled)
  const float* W1   = (const float*)d_in[2];
  const float* as1w = (const float*)d_in[3];
  const float* ad1w = (const float*)d_in[4];
  const float* b1   = (const float*)d_in[5];
  const float* W2   = (const float*)d_in[6];
  const float* as2w = (const float*)d_in[7];
  const float* ad2w = (const float*)d_in[8];
  const float* b2   = (const float*)d_in[9];
  float* out = (float*)d_out;
  const int N = in_sizes[0] / 128;
  const int E = in_sizes[1] / 2;

  char* p = (char*)d_ws;
  auto alloc = [&](size_t bytes) -> void* {
    void* r = (void*)p;
    p += (bytes + 511) & ~(size_t)511;
    return r;
  };
  int*            deg      = (int*)           alloc((size_t)N * 4);
  int*            cursor   = (int*)           alloc((size_t)N * 4);
  int*            partials = (int*)           alloc(64 * 4);
  int*            col      = (int*)           alloc((size_t)E * 4);
  int*            dstv     = (int*)           alloc((size_t)E * 4);
  float*          a_s1     = (float*)         alloc((size_t)N * 8 * 4);
  float*          a_d1     = (float*)         alloc((size_t)N * 8 * 4);
  unsigned short* w1w      = (unsigned short*)alloc((size_t)E * 8 * 2);
  unsigned short* w2w      = (unsigned short*)alloc((size_t)E * 2);
  float*          out1     = (float*)         alloc((size_t)N * 128 * 4);
  unsigned short* h1b      = (unsigned short*)alloc((size_t)N * 128 * 2);
  // layer-2 temporaries overlay h1b (dead after agg1)
  unsigned short* h2b  = h1b;                                 // N*40 bf16
  float*          a_s2 = (float*)(h1b + (size_t)N * 64);      // N floats (aligned region past h2b)
  float*          a_d2 = a_s2 + N;

  hipMemsetAsync(deg, 0, (size_t)N * 4, stream);

  int gE = (E + TB - 1) / TB;
  int nchunk = (N + SCAN_C - 1) / SCAN_C;

  k_hist    <<<gE, TB, 0, stream>>>(ei, E, N, deg);
  k_scan1   <<<nchunk, SCAN_T, 0, stream>>>(deg, N, cursor, partials);
  k_scan2   <<<1, 64, 0, stream>>>(partials, nchunk);
  k_scan3   <<<(N + TB - 1) / TB, TB, 0, stream>>>(cursor, N, partials);
  k_scatter <<<gE, TB, 0, stream>>>(ei, E, N, cursor, col, dstv);

  k_gemm1   <<<(N + 127) / 128, 256, 0, stream>>>(x, W1, h1b, N);
  k_att1    <<<(N * 8 + TB - 1) / TB, TB, 0, stream>>>(h1b, as1w, ad1w, a_s1, a_d1, N * 8);
  k_weights1<<<gE, TB, 0, stream>>>(col, dstv, a_s1, a_d1, w1w, E);
  k_agg1    <<<(N + 1) / 2, TB, 0, stream>>>(h1b, a_s1, a_d1, col, w1w, cursor, deg, b1, out1, N);

  k_gemm2   <<<(N + 255) / 256, 256, 0, stream>>>(out1, W2, h2b, N);
  k_att2    <<<(N + 31) / 32, TB, 0, stream>>>(h2b, as2w, ad2w, a_s2, a_d2, N);
  k_weights2<<<gE, TB, 0, stream>>>(col, dstv, a_s2, a_d2, w2w, E);
  k_agg2    <<<(N + 3) / 4, TB, 0, stream>>>(h2b, a_s2, a_d2, col, w2w, cursor, deg, b2, out, N);
}

// Round 4
// 516.622 us; speedup vs baseline: 1.1792x; 1.0982x over previous
//
#include <hip/hip_runtime.h>
#include <hip/hip_bf16.h>
#include <cstdint>

#define TB 256
#define SCAN_T 256
#define SCAN_C 2048

__device__ __forceinline__ float lrelu_exp(float e){
  e = e > 0.0f ? e : 0.2f * e;
  return __expf(e);
}
__device__ __forceinline__ unsigned short f2bf(float f){
  unsigned u = __float_as_uint(f);
  u = (u + 0x7fffu + ((u >> 16) & 1u)) >> 16;   // RNE
  return (unsigned short)u;
}
__device__ __forceinline__ float bf2f(unsigned short s){
  return __uint_as_float(((unsigned)s) << 16);
}
__device__ __forceinline__ float lof(unsigned u){ return __uint_as_float(u << 16); }
__device__ __forceinline__ float hif(unsigned u){ return __uint_as_float(u & 0xffff0000u); }
__device__ __forceinline__ unsigned pack2(float a, float b){
  return (unsigned)f2bf(a) | ((unsigned)f2bf(b) << 16);
}

// ---------------- CSR build (dst-indexed) ----------------
__global__ __launch_bounds__(TB) void k_hist(const int* __restrict__ ei, int E, int n, int* __restrict__ deg){
  int e = blockIdx.x * TB + threadIdx.x;
  if (e >= E) return;
  int d = ei[E + e];
  if ((unsigned)d < (unsigned)n) atomicAdd(&deg[d], 1);
}

__global__ __launch_bounds__(SCAN_T) void k_scan1(const int* __restrict__ deg, int n,
                                                  int* __restrict__ excl, int* __restrict__ partials){
  __shared__ int sums[SCAN_T];
  int t = threadIdx.x;
  int base = blockIdx.x * SCAN_C + t * 8;
  int v[8]; int s = 0;
  #pragma unroll
  for (int i = 0; i < 8; ++i){ int idx = base + i; v[i] = (idx < n) ? deg[idx] : 0; s += v[i]; }
  sums[t] = s;
  __syncthreads();
  for (int off = 1; off < SCAN_T; off <<= 1){
    int add = (t >= off) ? sums[t - off] : 0;
    __syncthreads();
    sums[t] += add;
    __syncthreads();
  }
  int run = sums[t] - s;
  if (t == SCAN_T - 1) partials[blockIdx.x] = sums[t];
  #pragma unroll
  for (int i = 0; i < 8; ++i){ int idx = base + i; if (idx < n) excl[idx] = run; run += v[i]; }
}

__global__ void k_scan2(int* partials, int nb){
  int lane = threadIdx.x;
  int orig = (lane < nb) ? partials[lane] : 0;
  int v = orig;
  for (int off = 1; off < 64; off <<= 1){
    int u = __shfl_up(v, off);
    if (lane >= off) v += u;
  }
  if (lane < nb) partials[lane] = v - orig;
}

__global__ __launch_bounds__(TB) void k_scan3(int* __restrict__ excl, int n, const int* __restrict__ partials){
  int i = blockIdx.x * TB + threadIdx.x;
  if (i < n) excl[i] += partials[i / SCAN_C];
}

__global__ __launch_bounds__(TB) void k_scatter(const int* __restrict__ ei, int E, int n,
                                                int* __restrict__ cursor, int2* __restrict__ sd){
  int e = blockIdx.x * TB + threadIdx.x;
  if (e >= E) return;
  int s = ei[e];
  int d = ei[E + e];
  if ((unsigned)d >= (unsigned)n || (unsigned)s >= (unsigned)n) return;
  int pos = atomicAdd(&cursor[d], 1);
  sd[pos] = make_int2(s, d);
}

// ---------------- GEMM1: h1b[N,128](bf16) = x[N,128] @ W1[128,128] ----------------
__global__ __launch_bounds__(256) void k_gemm1(const float* __restrict__ x, const float* __restrict__ W,
                                               unsigned short* __restrict__ hb, int n){
  __shared__ float xs[32][128];
  __shared__ float ws[32][128];
  int t = threadIdx.x;
  int ng = t & 15, cg = t >> 4;
  int node0 = blockIdx.x * 128;
  int nodeL = t >> 1, kh = t & 1;
  float acc[8][8];
  #pragma unroll
  for (int i = 0; i < 8; ++i)
    #pragma unroll
    for (int j = 0; j < 8; ++j) acc[i][j] = 0.0f;

  for (int kc = 0; kc < 4; ++kc){
    int k0 = kc * 32;
    __syncthreads();
    {
      int gn = node0 + nodeL;
      const float4* src = (const float4*)(x + (size_t)gn * 128 + k0 + kh * 16);
      #pragma unroll
      for (int u = 0; u < 4; ++u){
        float4 f = (gn < n) ? src[u] : make_float4(0.f, 0.f, 0.f, 0.f);
        int kk = kh * 16 + u * 4;
        xs[kk + 0][nodeL] = f.x; xs[kk + 1][nodeL] = f.y;
        xs[kk + 2][nodeL] = f.z; xs[kk + 3][nodeL] = f.w;
      }
      const float4* wsrc = (const float4*)(W + (size_t)k0 * 128);
      float4* wdst = (float4*)(&ws[0][0]);
      #pragma unroll
      for (int u = 0; u < 4; ++u) wdst[t + 256 * u] = wsrc[t + 256 * u];
    }
    __syncthreads();
    #pragma unroll 8
    for (int k = 0; k < 32; ++k){
      float xv[8];
      #pragma unroll
      for (int i = 0; i < 8; ++i) xv[i] = xs[k][ng + 16 * i];
      float4 w0 = *(const float4*)&ws[k][cg * 8];
      float4 w1 = *(const float4*)&ws[k][cg * 8 + 4];
      float wv[8] = {w0.x, w0.y, w0.z, w0.w, w1.x, w1.y, w1.z, w1.w};
      #pragma unroll
      for (int i = 0; i < 8; ++i)
        #pragma unroll
        for (int j = 0; j < 8; ++j) acc[i][j] = fmaf(xv[i], wv[j], acc[i][j]);
    }
  }
  #pragma unroll
  for (int i = 0; i < 8; ++i){
    int gn = node0 + ng + 16 * i;
    if (gn < n){
      uint4 o;
      o.x = pack2(acc[i][0], acc[i][1]);
      o.y = pack2(acc[i][2], acc[i][3]);
      o.z = pack2(acc[i][4], acc[i][5]);
      o.w = pack2(acc[i][6], acc[i][7]);
      *(uint4*)(hb + (size_t)gn * 128 + cg * 8) = o;
    }
  }
}

// ---------------- att1: a_s/a_d [N,8] from h1b ----------------
__global__ __launch_bounds__(TB) void k_att1(const unsigned short* __restrict__ hb, const float* __restrict__ asw,
                                             const float* __restrict__ adw,
                                             float* __restrict__ a_s, float* __restrict__ a_d, int n8){
  int idx = blockIdx.x * TB + threadIdx.x;   // node*8 + h
  if (idx >= n8) return;
  int h = idx & 7;
  uint4 lo4 = *(const uint4*)(hb + (size_t)idx * 16);
  uint4 hi4 = *(const uint4*)(hb + (size_t)idx * 16 + 8);
  float v[16];
  unsigned w_[8] = {lo4.x, lo4.y, lo4.z, lo4.w, hi4.x, hi4.y, hi4.z, hi4.w};
  #pragma unroll
  for (int u = 0; u < 8; ++u){
    v[2 * u]     = lof(w_[u]);
    v[2 * u + 1] = hif(w_[u]);
  }
  float ss = 0.f, dd = 0.f;
  #pragma unroll
  for (int u = 0; u < 16; ++u){
    ss = fmaf(v[u], asw[h * 16 + u], ss);
    dd = fmaf(v[u], adw[h * 16 + u], dd);
  }
  a_s[idx] = ss; a_d[idx] = dd;
}

// ---------------- weights1: w1w[pos][8] (bf16) ----------------
__global__ __launch_bounds__(TB) void k_weights1(const int2* __restrict__ sd,
                                                 const float* __restrict__ a_s, const float* __restrict__ a_d,
                                                 unsigned short* __restrict__ w1w, int E){
  int pos = blockIdx.x * TB + threadIdx.x;
  if (pos >= E) return;
  int2 e = sd[pos];
  int s = e.x, d = e.y;
  float4 as0 = *(const float4*)(a_s + (size_t)s * 8);
  float4 as1 = *(const float4*)(a_s + (size_t)s * 8 + 4);
  float4 ad0 = *(const float4*)(a_d + (size_t)d * 8);
  float4 ad1 = *(const float4*)(a_d + (size_t)d * 8 + 4);
  uint4 o;
  o.x = pack2(lrelu_exp(as0.x + ad0.x), lrelu_exp(as0.y + ad0.y));
  o.y = pack2(lrelu_exp(as0.z + ad0.z), lrelu_exp(as0.w + ad0.w));
  o.z = pack2(lrelu_exp(as1.x + ad1.x), lrelu_exp(as1.y + ad1.y));
  o.w = pack2(lrelu_exp(as1.z + ad1.z), lrelu_exp(as1.w + ad1.w));
  *(uint4*)(w1w + (size_t)pos * 8) = o;
}

// ---------------- agg1: out1b = relu(softmax-agg(h1b) + b1), 1 wave/node ----------------
__global__ __launch_bounds__(256) void k_agg1(const unsigned short* __restrict__ hb, const float* __restrict__ a_s,
    const float* __restrict__ a_d, const int2* __restrict__ sd, const unsigned short* __restrict__ w1w,
    const int* __restrict__ cursor, const int* __restrict__ deg,
    const float* __restrict__ b1, unsigned short* __restrict__ out1b, int n){
  int lane = threadIdx.x & 63;                 // channel pair: 2*lane, 2*lane+1
  int node = blockIdx.x * 4 + (threadIdx.x >> 6);
  if (node >= n) return;
  int h = lane >> 3;
  float wSelf = lrelu_exp(a_s[(size_t)node * 8 + h] + a_d[(size_t)node * 8 + h]);
  unsigned hv = *(const unsigned*)(hb + (size_t)node * 128 + lane * 2);
  float acc0 = wSelf * lof(hv), acc1 = wSelf * hif(hv);
  float denom = wSelf;
  int end = cursor[node];
  int pp = end - deg[node];
  for (; pp + 8 <= end; pp += 8){
    int   s[8]; float w[8]; unsigned v[8];
    #pragma unroll
    for (int u = 0; u < 8; ++u) s[u] = sd[pp + u].x;
    #pragma unroll
    for (int u = 0; u < 8; ++u) w[u] = bf2f(w1w[(size_t)(pp + u) * 8 + h]);
    #pragma unroll
    for (int u = 0; u < 8; ++u) v[u] = *(const unsigned*)(hb + (size_t)s[u] * 128 + lane * 2);
    #pragma unroll
    for (int u = 0; u < 8; ++u){
      acc0 = fmaf(w[u], lof(v[u]), acc0);
      acc1 = fmaf(w[u], hif(v[u]), acc1);
      denom += w[u];
    }
  }
  for (; pp + 4 <= end; pp += 4){
    int   s[4]; float w[4]; unsigned v[4];
    #pragma unroll
    for (int u = 0; u < 4; ++u) s[u] = sd[pp + u].x;
    #pragma unroll
    for (int u = 0; u < 4; ++u) w[u] = bf2f(w1w[(size_t)(pp + u) * 8 + h]);
    #pragma unroll
    for (int u = 0; u < 4; ++u) v[u] = *(const unsigned*)(hb + (size_t)s[u] * 128 + lane * 2);
    #pragma unroll
    for (int u = 0; u < 4; ++u){
      acc0 = fmaf(w[u], lof(v[u]), acc0);
      acc1 = fmaf(w[u], hif(v[u]), acc1);
      denom += w[u];
    }
  }
  for (; pp < end; ++pp){
    int s0 = sd[pp].x;
    float w0 = bf2f(w1w[(size_t)pp * 8 + h]);
    unsigned v0 = *(const unsigned*)(hb + (size_t)s0 * 128 + lane * 2);
    acc0 = fmaf(w0, lof(v0), acc0);
    acc1 = fmaf(w0, hif(v0), acc1);
    denom += w0;
  }
  float inv = 1.0f / denom;
  float2 bb = *(const float2*)(b1 + lane * 2);
  float o0 = fmaf(acc0, inv, bb.x);
  float o1 = fmaf(acc1, inv, bb.y);
  o0 = o0 > 0.0f ? o0 : 0.0f;
  o1 = o1 > 0.0f ? o1 : 0.0f;
  ((unsigned*)out1b)[(size_t)node * 64 + lane] = pack2(o0, o1);
}

// ---------------- GEMM2: h2b[N,40](bf16) = out1b[N,128](bf16) @ W2[128,40] ----------------
__global__ __launch_bounds__(256) void k_gemm2(const unsigned short* __restrict__ ab, const float* __restrict__ W2,
                                               unsigned short* __restrict__ h2b, int n){
  __shared__ float xs[32][256];
  __shared__ float ws[128][40];
  int t = threadIdx.x;
  for (int i = t; i < 128 * 40; i += 256) (&ws[0][0])[i] = W2[i];
  int ng = t & 63, cg = t >> 6;
  int node0 = blockIdx.x * 256;
  float acc[4][10];
  #pragma unroll
  for (int i = 0; i < 4; ++i)
    #pragma unroll
    for (int j = 0; j < 10; ++j) acc[i][j] = 0.0f;

  for (int kc = 0; kc < 4; ++kc){
    int k0 = kc * 32;
    __syncthreads();
    {
      int gn = node0 + t;
      uint4 q[2];
      if (gn < n){
        const uint4* src = (const uint4*)(ab + (size_t)gn * 128 + k0);
        q[0] = src[0]; q[1] = src[1];
      } else {
        q[0] = make_uint4(0,0,0,0); q[1] = make_uint4(0,0,0,0);
      }
      #pragma unroll
      for (int u = 0; u < 2; ++u){
        unsigned w4[4] = {q[u].x, q[u].y, q[u].z, q[u].w};
        #pragma unroll
        for (int j = 0; j < 4; ++j){
          int kk = u * 8 + j * 2;
          xs[kk][t]     = lof(w4[j]);
          xs[kk + 1][t] = hif(w4[j]);
        }
      }
      // second half of the 32-k chunk
      uint4 r[2];
      if (gn < n){
        const uint4* src = (const uint4*)(ab + (size_t)gn * 128 + k0 + 16);
        r[0] = src[0]; r[1] = src[1];
      } else {
        r[0] = make_uint4(0,0,0,0); r[1] = make_uint4(0,0,0,0);
      }
      #pragma unroll
      for (int u = 0; u < 2; ++u){
        unsigned w4[4] = {r[u].x, r[u].y, r[u].z, r[u].w};
        #pragma unroll
        for (int j = 0; j < 4; ++j){
          int kk = 16 + u * 8 + j * 2;
          xs[kk][t]     = lof(w4[j]);
          xs[kk + 1][t] = hif(w4[j]);
        }
      }
    }
    __syncthreads();
    #pragma unroll 4
    for (int k = 0; k < 32; ++k){
      float xv[4];
      #pragma unroll
      for (int i = 0; i < 4; ++i) xv[i] = xs[k][ng + 64 * i];
      float wv[10];
      #pragma unroll
      for (int j = 0; j < 10; ++j) wv[j] = ws[k0 + k][cg * 10 + j];
      #pragma unroll
      for (int i = 0; i < 4; ++i)
        #pragma unroll
        for (int j = 0; j < 10; ++j) acc[i][j] = fmaf(xv[i], wv[j], acc[i][j]);
    }
  }
  #pragma unroll
  for (int i = 0; i < 4; ++i){
    int gn = node0 + ng + 64 * i;
    if (gn < n){
      unsigned pk[5];
      #pragma unroll
      for (int j = 0; j < 5; ++j) pk[j] = pack2(acc[i][2 * j], acc[i][2 * j + 1]);
      unsigned* dst = (unsigned*)(h2b + (size_t)gn * 40 + cg * 10);
      #pragma unroll
      for (int j = 0; j < 5; ++j) dst[j] = pk[j];
    }
  }
}

// ---------------- att2: a_s/a_d [N] from h2b ----------------
__global__ __launch_bounds__(TB) void k_att2(const unsigned short* __restrict__ h2b, const float* __restrict__ asw,
                                             const float* __restrict__ adw,
                                             float* __restrict__ a_s, float* __restrict__ a_d, int n){
  int t = threadIdx.x;
  int node = blockIdx.x * 32 + (t >> 3);
  int sub = t & 7;
  if (node >= n) return;
  float ss = 0.f, dd = 0.f;
  for (int j = sub; j < 40; j += 8){
    float v = bf2f(h2b[(size_t)node * 40 + j]);
    ss = fmaf(v, asw[j], ss);
    dd = fmaf(v, adw[j], dd);
  }
  #pragma unroll
  for (int off = 1; off < 8; off <<= 1){
    ss += __shfl_xor(ss, off);
    dd += __shfl_xor(dd, off);
  }
  if (sub == 0){ a_s[node] = ss; a_d[node] = dd; }
}

// ---------------- weights2: w2w[pos] (bf16) ----------------
__global__ __launch_bounds__(TB) void k_weights2(const int2* __restrict__ sd,
                                                 const float* __restrict__ a_s, const float* __restrict__ a_d,
                                                 unsigned short* __restrict__ w2w, int E){
  int pos = blockIdx.x * TB + threadIdx.x;
  if (pos >= E) return;
  int2 e = sd[pos];
  w2w[pos] = f2bf(lrelu_exp(a_s[e.x] + a_d[e.y]));
}

// ---------------- agg2 + log_softmax -> out ----------------
__global__ __launch_bounds__(TB) void k_agg2(const unsigned short* __restrict__ h2b, const float* __restrict__ a_s,
    const float* __restrict__ a_d, const int2* __restrict__ sd, const unsigned short* __restrict__ w2w,
    const int* __restrict__ cursor, const int* __restrict__ deg,
    const float* __restrict__ b2, float* __restrict__ out, int n){
  int lane = threadIdx.x & 63;
  int node = blockIdx.x * 4 + (threadIdx.x >> 6);
  if (node >= n) return;
  bool act = lane < 40;
  float w = lrelu_exp(a_s[node] + a_d[node]);       // self-loop
  float acc = w * (act ? bf2f(h2b[(size_t)node * 40 + lane]) : 0.0f);
  float denom = w;
  int end = cursor[node];
  int pp = end - deg[node];
  for (; pp + 8 <= end; pp += 8){
    int s[8]; float wv[8]; float v[8];
    #pragma unroll
    for (int u = 0; u < 8; ++u) s[u] = sd[pp + u].x;
    #pragma unroll
    for (int u = 0; u < 8; ++u) wv[u] = bf2f(w2w[pp + u]);
    #pragma unroll
    for (int u = 0; u < 8; ++u) v[u] = act ? bf2f(h2b[(size_t)s[u] * 40 + lane]) : 0.0f;
    #pragma unroll
    for (int u = 0; u < 8; ++u){ acc = fmaf(wv[u], v[u], acc); denom += wv[u]; }
  }
  for (; pp < end; ++pp){
    float w0 = bf2f(w2w[pp]);
    acc = fmaf(w0, act ? bf2f(h2b[(size_t)sd[pp].x * 40 + lane]) : 0.0f, acc);
    denom += w0;
  }
  float v = act ? (acc / denom + b2[lane]) : -1e30f;
  float m = v;
  #pragma unroll
  for (int off = 32; off >= 1; off >>= 1) m = fmaxf(m, __shfl_xor(m, off));
  float ex = act ? __expf(v - m) : 0.0f;
  float S = ex;
  #pragma unroll
  for (int off = 32; off >= 1; off >>= 1) S += __shfl_xor(S, off);
  if (act) out[(size_t)node * 40 + lane] = v - m - __logf(S);
}

extern "C" void kernel_launch(void* const* d_in, const int* in_sizes, int n_in,
                              void* d_out, int out_size, void* d_ws, size_t ws_size,
                              hipStream_t stream){
  const float* x    = (const float*)d_in[0];
  const int*   ei   = (const int*)d_in[1];          // int32 (jax x64 disabled)
  const float* W1   = (const float*)d_in[2];
  const float* as1w = (const float*)d_in[3];
  const float* ad1w = (const float*)d_in[4];
  const float* b1   = (const float*)d_in[5];
  const float* W2   = (const float*)d_in[6];
  const float* as2w = (const float*)d_in[7];
  const float* ad2w = (const float*)d_in[8];
  const float* b2   = (const float*)d_in[9];
  float* out = (float*)d_out;
  const int N = in_sizes[0] / 128;
  const int E = in_sizes[1] / 2;

  char* p = (char*)d_ws;
  auto alloc = [&](size_t bytes) -> void* {
    void* r = (void*)p;
    p += (bytes + 511) & ~(size_t)511;
    return r;
  };
  int*            deg      = (int*)           alloc((size_t)N * 4);
  int*            cursor   = (int*)           alloc((size_t)N * 4);
  int*            partials = (int*)           alloc(64 * 4);
  int2*           sd       = (int2*)          alloc((size_t)E * 8);
  float*          a_s1     = (float*)         alloc((size_t)N * 8 * 4);
  float*          a_d1     = (float*)         alloc((size_t)N * 8 * 4);
  unsigned short* w1w      = (unsigned short*)alloc((size_t)E * 8 * 2);
  unsigned short* w2w      = (unsigned short*)alloc((size_t)E * 2);
  unsigned short* out1b    = (unsigned short*)alloc((size_t)N * 128 * 2);
  unsigned short* h1b      = (unsigned short*)alloc((size_t)N * 128 * 2);
  // layer-2 temporaries overlay h1b (dead after agg1)
  unsigned short* h2b  = h1b;                                 // N*40 bf16
  float*          a_s2 = (float*)((char*)h1b + (size_t)N * 128);  // past h2b, within h1b region
  float*          a_d2 = a_s2 + N;

  hipMemsetAsync(deg, 0, (size_t)N * 4, stream);

  int gE = (E + TB - 1) / TB;
  int nchunk = (N + SCAN_C - 1) / SCAN_C;

  k_hist    <<<gE, TB, 0, stream>>>(ei, E, N, deg);
  k_scan1   <<<nchunk, SCAN_T, 0, stream>>>(deg, N, cursor, partials);
  k_scan2   <<<1, 64, 0, stream>>>(partials, nchunk);
  k_scan3   <<<(N + TB - 1) / TB, TB, 0, stream>>>(cursor, N, partials);
  k_scatter <<<gE, TB, 0, stream>>>(ei, E, N, cursor, sd);

  k_gemm1   <<<(N + 127) / 128, 256, 0, stream>>>(x, W1, h1b, N);
  k_att1    <<<(N * 8 + TB - 1) / TB, TB, 0, stream>>>(h1b, as1w, ad1w, a_s1, a_d1, N * 8);
  k_weights1<<<gE, TB, 0, stream>>>(sd, a_s1, a_d1, w1w, E);
  k_agg1    <<<(N + 3) / 4, 256, 0, stream>>>(h1b, a_s1, a_d1, sd, w1w, cursor, deg, b1, out1b, N);

  k_gemm2   <<<(N + 255) / 256, 256, 0, stream>>>(out1b, W2, h2b, N);
  k_att2    <<<(N + 31) / 32, TB, 0, stream>>>(h2b, as2w, ad2w, a_s2, a_d2, N);
  k_weights2<<<gE, TB, 0, stream>>>(sd, a_s2, a_d2, w2w, E);
  k_agg2    <<<(N + 3) / 4, TB, 0, stream>>>(h2b, a_s2, a_d2, sd, w2w, cursor, deg, b2, out, N);
}

// Round 5
// 422.708 us; speedup vs baseline: 1.4412x; 1.2222x over previous
//
#include <hip/hip_runtime.h>
#include <hip/hip_bf16.h>
#include <cstdint>

#define TB 256
#define SCAN_T 256
#define SCAN_C 2048

__device__ __forceinline__ float lrelu_exp(float e){
  e = e > 0.0f ? e : 0.2f * e;
  return __expf(e);
}
__device__ __forceinline__ unsigned short f2bf(float f){
  unsigned u = __float_as_uint(f);
  u = (u + 0x7fffu + ((u >> 16) & 1u)) >> 16;   // RNE
  return (unsigned short)u;
}
__device__ __forceinline__ float bf2f(unsigned short s){
  return __uint_as_float(((unsigned)s) << 16);
}
__device__ __forceinline__ float lof(unsigned u){ return __uint_as_float(u << 16); }
__device__ __forceinline__ float hif(unsigned u){ return __uint_as_float(u & 0xffff0000u); }
__device__ __forceinline__ unsigned pack2(float a, float b){
  return (unsigned)f2bf(a) | ((unsigned)f2bf(b) << 16);
}

// ---------------- CSR build (dst-indexed) ----------------
// histogram + rank capture, 4 edges/thread for atomic-latency hiding
__global__ __launch_bounds__(TB) void k_histrank(const int* __restrict__ ei, int E, int n,
                                                 int* __restrict__ deg, int* __restrict__ rank){
  int b0 = blockIdx.x * (TB * 4) + threadIdx.x;
  int d[4]; int r[4]; bool ok[4];
  #pragma unroll
  for (int u = 0; u < 4; ++u){
    int e = b0 + u * TB;
    ok[u] = (e < E);
    d[u] = ok[u] ? ei[E + e] : 0;
    ok[u] = ok[u] && ((unsigned)d[u] < (unsigned)n);
  }
  #pragma unroll
  for (int u = 0; u < 4; ++u)
    if (ok[u]) r[u] = atomicAdd(&deg[d[u]], 1);
  #pragma unroll
  for (int u = 0; u < 4; ++u)
    if (ok[u]) rank[b0 + u * TB] = r[u];
}

__global__ __launch_bounds__(SCAN_T) void k_scan1(const int* __restrict__ deg, int n,
                                                  int* __restrict__ excl, int* __restrict__ partials){
  __shared__ int sums[SCAN_T];
  int t = threadIdx.x;
  int base = blockIdx.x * SCAN_C + t * 8;
  int v[8]; int s = 0;
  #pragma unroll
  for (int i = 0; i < 8; ++i){ int idx = base + i; v[i] = (idx < n) ? deg[idx] : 0; s += v[i]; }
  sums[t] = s;
  __syncthreads();
  for (int off = 1; off < SCAN_T; off <<= 1){
    int add = (t >= off) ? sums[t - off] : 0;
    __syncthreads();
    sums[t] += add;
    __syncthreads();
  }
  int run = sums[t] - s;
  if (t == SCAN_T - 1) partials[blockIdx.x] = sums[t];
  #pragma unroll
  for (int i = 0; i < 8; ++i){ int idx = base + i; if (idx < n) excl[idx] = run; run += v[i]; }
}

__global__ void k_scan2(int* partials, int nb){
  int lane = threadIdx.x;
  int orig = (lane < nb) ? partials[lane] : 0;
  int v = orig;
  for (int off = 1; off < 64; off <<= 1){
    int u = __shfl_up(v, off);
    if (lane >= off) v += u;
  }
  if (lane < nb) partials[lane] = v - orig;
}

__global__ __launch_bounds__(TB) void k_scan3(int* __restrict__ excl, int n, const int* __restrict__ partials){
  int i = blockIdx.x * TB + threadIdx.x;
  if (i < n) excl[i] += partials[i / SCAN_C];
}

// scatter without atomics: pos = excl[d] + rank[e]
__global__ __launch_bounds__(TB) void k_scatter(const int* __restrict__ ei, int E, int n,
                                                const int* __restrict__ excl, const int* __restrict__ rank,
                                                int2* __restrict__ sd){
  int b0 = blockIdx.x * (TB * 4) + threadIdx.x;
  #pragma unroll
  for (int u = 0; u < 4; ++u){
    int e = b0 + u * TB;
    if (e >= E) continue;
    int s = ei[e];
    int d = ei[E + e];
    if ((unsigned)d >= (unsigned)n || (unsigned)s >= (unsigned)n) continue;
    int pos = excl[d] + rank[e];
    sd[pos] = make_int2(s, d);
  }
}

// ---------------- GEMM1: h1b[N,128](bf16) = x[N,128] @ W1[128,128] ----------------
__global__ __launch_bounds__(256) void k_gemm1(const float* __restrict__ x, const float* __restrict__ W,
                                               unsigned short* __restrict__ hb, int n){
  __shared__ float xs[32][128];
  __shared__ float ws[32][128];
  int t = threadIdx.x;
  int ng = t & 15, cg = t >> 4;
  int node0 = blockIdx.x * 128;
  int nodeL = t >> 1, kh = t & 1;
  float acc[8][8];
  #pragma unroll
  for (int i = 0; i < 8; ++i)
    #pragma unroll
    for (int j = 0; j < 8; ++j) acc[i][j] = 0.0f;

  for (int kc = 0; kc < 4; ++kc){
    int k0 = kc * 32;
    __syncthreads();
    {
      int gn = node0 + nodeL;
      const float4* src = (const float4*)(x + (size_t)gn * 128 + k0 + kh * 16);
      #pragma unroll
      for (int u = 0; u < 4; ++u){
        float4 f = (gn < n) ? src[u] : make_float4(0.f, 0.f, 0.f, 0.f);
        int kk = kh * 16 + u * 4;
        xs[kk + 0][nodeL] = f.x; xs[kk + 1][nodeL] = f.y;
        xs[kk + 2][nodeL] = f.z; xs[kk + 3][nodeL] = f.w;
      }
      const float4* wsrc = (const float4*)(W + (size_t)k0 * 128);
      float4* wdst = (float4*)(&ws[0][0]);
      #pragma unroll
      for (int u = 0; u < 4; ++u) wdst[t + 256 * u] = wsrc[t + 256 * u];
    }
    __syncthreads();
    #pragma unroll 8
    for (int k = 0; k < 32; ++k){
      float xv[8];
      #pragma unroll
      for (int i = 0; i < 8; ++i) xv[i] = xs[k][ng + 16 * i];
      float4 w0 = *(const float4*)&ws[k][cg * 8];
      float4 w1 = *(const float4*)&ws[k][cg * 8 + 4];
      float wv[8] = {w0.x, w0.y, w0.z, w0.w, w1.x, w1.y, w1.z, w1.w};
      #pragma unroll
      for (int i = 0; i < 8; ++i)
        #pragma unroll
        for (int j = 0; j < 8; ++j) acc[i][j] = fmaf(xv[i], wv[j], acc[i][j]);
    }
  }
  #pragma unroll
  for (int i = 0; i < 8; ++i){
    int gn = node0 + ng + 16 * i;
    if (gn < n){
      uint4 o;
      o.x = pack2(acc[i][0], acc[i][1]);
      o.y = pack2(acc[i][2], acc[i][3]);
      o.z = pack2(acc[i][4], acc[i][5]);
      o.w = pack2(acc[i][6], acc[i][7]);
      *(uint4*)(hb + (size_t)gn * 128 + cg * 8) = o;
    }
  }
}

// ---------------- att1: a_s/a_d [N,8] from h1b ----------------
__global__ __launch_bounds__(TB) void k_att1(const unsigned short* __restrict__ hb, const float* __restrict__ asw,
                                             const float* __restrict__ adw,
                                             float* __restrict__ a_s, float* __restrict__ a_d, int n8){
  int idx = blockIdx.x * TB + threadIdx.x;   // node*8 + h
  if (idx >= n8) return;
  int h = idx & 7;
  uint4 lo4 = *(const uint4*)(hb + (size_t)idx * 16);
  uint4 hi4 = *(const uint4*)(hb + (size_t)idx * 16 + 8);
  float v[16];
  unsigned w_[8] = {lo4.x, lo4.y, lo4.z, lo4.w, hi4.x, hi4.y, hi4.z, hi4.w};
  #pragma unroll
  for (int u = 0; u < 8; ++u){
    v[2 * u]     = lof(w_[u]);
    v[2 * u + 1] = hif(w_[u]);
  }
  float ss = 0.f, dd = 0.f;
  #pragma unroll
  for (int u = 0; u < 16; ++u){
    ss = fmaf(v[u], asw[h * 16 + u], ss);
    dd = fmaf(v[u], adw[h * 16 + u], dd);
  }
  a_s[idx] = ss; a_d[idx] = dd;
}

// ---------------- weights1: w1w[pos][8] (bf16) ----------------
__global__ __launch_bounds__(TB) void k_weights1(const int2* __restrict__ sd,
                                                 const float* __restrict__ a_s, const float* __restrict__ a_d,
                                                 unsigned short* __restrict__ w1w, int E){
  int pos = blockIdx.x * TB + threadIdx.x;
  if (pos >= E) return;
  int2 e = sd[pos];
  int s = e.x, d = e.y;
  float4 as0 = *(const float4*)(a_s + (size_t)s * 8);
  float4 as1 = *(const float4*)(a_s + (size_t)s * 8 + 4);
  float4 ad0 = *(const float4*)(a_d + (size_t)d * 8);
  float4 ad1 = *(const float4*)(a_d + (size_t)d * 8 + 4);
  uint4 o;
  o.x = pack2(lrelu_exp(as0.x + ad0.x), lrelu_exp(as0.y + ad0.y));
  o.y = pack2(lrelu_exp(as0.z + ad0.z), lrelu_exp(as0.w + ad0.w));
  o.z = pack2(lrelu_exp(as1.x + ad1.x), lrelu_exp(as1.y + ad1.y));
  o.w = pack2(lrelu_exp(as1.z + ad1.z), lrelu_exp(as1.w + ad1.w));
  *(uint4*)(w1w + (size_t)pos * 8) = o;
}

// ---------------- agg1: out1b = relu(softmax-agg(h1b) + b1), 1 wave/node ----------------
__global__ __launch_bounds__(256) void k_agg1(const unsigned short* __restrict__ hb, const float* __restrict__ a_s,
    const float* __restrict__ a_d, const int2* __restrict__ sd, const unsigned short* __restrict__ w1w,
    const int* __restrict__ excl, const int* __restrict__ deg,
    const float* __restrict__ b1, unsigned short* __restrict__ out1b, int n){
  int lane = threadIdx.x & 63;                 // channel pair: 2*lane, 2*lane+1
  int node = blockIdx.x * 4 + (threadIdx.x >> 6);
  if (node >= n) return;
  int h = lane >> 3;
  float wSelf = lrelu_exp(a_s[(size_t)node * 8 + h] + a_d[(size_t)node * 8 + h]);
  unsigned hv = *(const unsigned*)(hb + (size_t)node * 128 + lane * 2);
  float acc0 = wSelf * lof(hv), acc1 = wSelf * hif(hv);
  float denom = wSelf;
  int pp = excl[node];
  int end = pp + deg[node];
  for (; pp + 8 <= end; pp += 8){
    int   s[8]; float w[8]; unsigned v[8];
    #pragma unroll
    for (int u = 0; u < 8; ++u) s[u] = sd[pp + u].x;
    #pragma unroll
    for (int u = 0; u < 8; ++u) w[u] = bf2f(w1w[(size_t)(pp + u) * 8 + h]);
    #pragma unroll
    for (int u = 0; u < 8; ++u) v[u] = *(const unsigned*)(hb + (size_t)s[u] * 128 + lane * 2);
    #pragma unroll
    for (int u = 0; u < 8; ++u){
      acc0 = fmaf(w[u], lof(v[u]), acc0);
      acc1 = fmaf(w[u], hif(v[u]), acc1);
      denom += w[u];
    }
  }
  for (; pp + 4 <= end; pp += 4){
    int   s[4]; float w[4]; unsigned v[4];
    #pragma unroll
    for (int u = 0; u < 4; ++u) s[u] = sd[pp + u].x;
    #pragma unroll
    for (int u = 0; u < 4; ++u) w[u] = bf2f(w1w[(size_t)(pp + u) * 8 + h]);
    #pragma unroll
    for (int u = 0; u < 4; ++u) v[u] = *(const unsigned*)(hb + (size_t)s[u] * 128 + lane * 2);
    #pragma unroll
    for (int u = 0; u < 4; ++u){
      acc0 = fmaf(w[u], lof(v[u]), acc0);
      acc1 = fmaf(w[u], hif(v[u]), acc1);
      denom += w[u];
    }
  }
  for (; pp < end; ++pp){
    int s0 = sd[pp].x;
    float w0 = bf2f(w1w[(size_t)pp * 8 + h]);
    unsigned v0 = *(const unsigned*)(hb + (size_t)s0 * 128 + lane * 2);
    acc0 = fmaf(w0, lof(v0), acc0);
    acc1 = fmaf(w0, hif(v0), acc1);
    denom += w0;
  }
  float inv = 1.0f / denom;
  float2 bb = *(const float2*)(b1 + lane * 2);
  float o0 = fmaf(acc0, inv, bb.x);
  float o1 = fmaf(acc1, inv, bb.y);
  o0 = o0 > 0.0f ? o0 : 0.0f;
  o1 = o1 > 0.0f ? o1 : 0.0f;
  ((unsigned*)out1b)[(size_t)node * 64 + lane] = pack2(o0, o1);
}

// ---------------- GEMM2: h2b[N,40](bf16) = out1b[N,128](bf16) @ W2[128,40] ----------------
__global__ __launch_bounds__(256) void k_gemm2(const unsigned short* __restrict__ ab, const float* __restrict__ W2,
                                               unsigned short* __restrict__ h2b, int n){
  __shared__ float xs[32][256];
  __shared__ float ws[128][40];
  int t = threadIdx.x;
  for (int i = t; i < 128 * 40; i += 256) (&ws[0][0])[i] = W2[i];
  int ng = t & 63, cg = t >> 6;
  int node0 = blockIdx.x * 256;
  float acc[4][10];
  #pragma unroll
  for (int i = 0; i < 4; ++i)
    #pragma unroll
    for (int j = 0; j < 10; ++j) acc[i][j] = 0.0f;

  for (int kc = 0; kc < 4; ++kc){
    int k0 = kc * 32;
    __syncthreads();
    {
      int gn = node0 + t;
      uint4 q[2];
      if (gn < n){
        const uint4* src = (const uint4*)(ab + (size_t)gn * 128 + k0);
        q[0] = src[0]; q[1] = src[1];
      } else {
        q[0] = make_uint4(0,0,0,0); q[1] = make_uint4(0,0,0,0);
      }
      #pragma unroll
      for (int u = 0; u < 2; ++u){
        unsigned w4[4] = {q[u].x, q[u].y, q[u].z, q[u].w};
        #pragma unroll
        for (int j = 0; j < 4; ++j){
          int kk = u * 8 + j * 2;
          xs[kk][t]     = lof(w4[j]);
          xs[kk + 1][t] = hif(w4[j]);
        }
      }
      uint4 r[2];
      if (gn < n){
        const uint4* src = (const uint4*)(ab + (size_t)gn * 128 + k0 + 16);
        r[0] = src[0]; r[1] = src[1];
      } else {
        r[0] = make_uint4(0,0,0,0); r[1] = make_uint4(0,0,0,0);
      }
      #pragma unroll
      for (int u = 0; u < 2; ++u){
        unsigned w4[4] = {r[u].x, r[u].y, r[u].z, r[u].w};
        #pragma unroll
        for (int j = 0; j < 4; ++j){
          int kk = 16 + u * 8 + j * 2;
          xs[kk][t]     = lof(w4[j]);
          xs[kk + 1][t] = hif(w4[j]);
        }
      }
    }
    __syncthreads();
    #pragma unroll 4
    for (int k = 0; k < 32; ++k){
      float xv[4];
      #pragma unroll
      for (int i = 0; i < 4; ++i) xv[i] = xs[k][ng + 64 * i];
      float wv[10];
      #pragma unroll
      for (int j = 0; j < 10; ++j) wv[j] = ws[k0 + k][cg * 10 + j];
      #pragma unroll
      for (int i = 0; i < 4; ++i)
        #pragma unroll
        for (int j = 0; j < 10; ++j) acc[i][j] = fmaf(xv[i], wv[j], acc[i][j]);
    }
  }
  #pragma unroll
  for (int i = 0; i < 4; ++i){
    int gn = node0 + ng + 64 * i;
    if (gn < n){
      unsigned pk[5];
      #pragma unroll
      for (int j = 0; j < 5; ++j) pk[j] = pack2(acc[i][2 * j], acc[i][2 * j + 1]);
      unsigned* dst = (unsigned*)(h2b + (size_t)gn * 40 + cg * 10);
      #pragma unroll
      for (int j = 0; j < 5; ++j) dst[j] = pk[j];
    }
  }
}

// ---------------- att2: a_s/a_d [N] from h2b ----------------
__global__ __launch_bounds__(TB) void k_att2(const unsigned short* __restrict__ h2b, const float* __restrict__ asw,
                                             const float* __restrict__ adw,
                                             float* __restrict__ a_s, float* __restrict__ a_d, int n){
  int t = threadIdx.x;
  int node = blockIdx.x * 32 + (t >> 3);
  int sub = t & 7;
  if (node >= n) return;
  float ss = 0.f, dd = 0.f;
  for (int j = sub; j < 40; j += 8){
    float v = bf2f(h2b[(size_t)node * 40 + j]);
    ss = fmaf(v, asw[j], ss);
    dd = fmaf(v, adw[j], dd);
  }
  #pragma unroll
  for (int off = 1; off < 8; off <<= 1){
    ss += __shfl_xor(ss, off);
    dd += __shfl_xor(dd, off);
  }
  if (sub == 0){ a_s[node] = ss; a_d[node] = dd; }
}

// ---------------- weights2: w2w[pos] (bf16) ----------------
__global__ __launch_bounds__(TB) void k_weights2(const int2* __restrict__ sd,
                                                 const float* __restrict__ a_s, const float* __restrict__ a_d,
                                                 unsigned short* __restrict__ w2w, int E){
  int pos = blockIdx.x * TB + threadIdx.x;
  if (pos >= E) return;
  int2 e = sd[pos];
  w2w[pos] = f2bf(lrelu_exp(a_s[e.x] + a_d[e.y]));
}

// ---------------- agg2 + log_softmax -> out ----------------
__global__ __launch_bounds__(TB) void k_agg2(const unsigned short* __restrict__ h2b, const float* __restrict__ a_s,
    const float* __restrict__ a_d, const int2* __restrict__ sd, const unsigned short* __restrict__ w2w,
    const int* __restrict__ excl, const int* __restrict__ deg,
    const float* __restrict__ b2, float* __restrict__ out, int n){
  int lane = threadIdx.x & 63;
  int node = blockIdx.x * 4 + (threadIdx.x >> 6);
  if (node >= n) return;
  bool act = lane < 40;
  float w = lrelu_exp(a_s[node] + a_d[node]);       // self-loop
  float acc = w * (act ? bf2f(h2b[(size_t)node * 40 + lane]) : 0.0f);
  float denom = w;
  int pp = excl[node];
  int end = pp + deg[node];
  for (; pp + 8 <= end; pp += 8){
    int s[8]; float wv[8]; float v[8];
    #pragma unroll
    for (int u = 0; u < 8; ++u) s[u] = sd[pp + u].x;
    #pragma unroll
    for (int u = 0; u < 8; ++u) wv[u] = bf2f(w2w[pp + u]);
    #pragma unroll
    for (int u = 0; u < 8; ++u) v[u] = act ? bf2f(h2b[(size_t)s[u] * 40 + lane]) : 0.0f;
    #pragma unroll
    for (int u = 0; u < 8; ++u){ acc = fmaf(wv[u], v[u], acc); denom += wv[u]; }
  }
  for (; pp < end; ++pp){
    float w0 = bf2f(w2w[pp]);
    acc = fmaf(w0, act ? bf2f(h2b[(size_t)sd[pp].x * 40 + lane]) : 0.0f, acc);
    denom += w0;
  }
  float v = act ? (acc / denom + b2[lane]) : -1e30f;
  float m = v;
  #pragma unroll
  for (int off = 32; off >= 1; off >>= 1) m = fmaxf(m, __shfl_xor(m, off));
  float ex = act ? __expf(v - m) : 0.0f;
  float S = ex;
  #pragma unroll
  for (int off = 32; off >= 1; off >>= 1) S += __shfl_xor(S, off);
  if (act) out[(size_t)node * 40 + lane] = v - m - __logf(S);
}

extern "C" void kernel_launch(void* const* d_in, const int* in_sizes, int n_in,
                              void* d_out, int out_size, void* d_ws, size_t ws_size,
                              hipStream_t stream){
  const float* x    = (const float*)d_in[0];
  const int*   ei   = (const int*)d_in[1];          // int32 (jax x64 disabled)
  const float* W1   = (const float*)d_in[2];
  const float* as1w = (const float*)d_in[3];
  const float* ad1w = (const float*)d_in[4];
  const float* b1   = (const float*)d_in[5];
  const float* W2   = (const float*)d_in[6];
  const float* as2w = (const float*)d_in[7];
  const float* ad2w = (const float*)d_in[8];
  const float* b2   = (const float*)d_in[9];
  float* out = (float*)d_out;
  const int N = in_sizes[0] / 128;
  const int E = in_sizes[1] / 2;

  char* p = (char*)d_ws;
  auto alloc = [&](size_t bytes) -> void* {
    void* r = (void*)p;
    p += (bytes + 511) & ~(size_t)511;
    return r;
  };
  int*            deg      = (int*)           alloc((size_t)N * 4);
  int*            excl     = (int*)           alloc((size_t)N * 4);
  int*            partials = (int*)           alloc(64 * 4);
  int*            rank     = (int*)           alloc((size_t)E * 4);
  int2*           sd       = (int2*)          alloc((size_t)E * 8);
  float*          a_s1     = (float*)         alloc((size_t)N * 8 * 4);
  float*          a_d1     = (float*)         alloc((size_t)N * 8 * 4);
  unsigned short* w1w      = (unsigned short*)alloc((size_t)E * 8 * 2);
  unsigned short* w2w      = (unsigned short*)alloc((size_t)E * 2);
  unsigned short* out1b    = (unsigned short*)alloc((size_t)N * 128 * 2);
  unsigned short* h1b      = (unsigned short*)alloc((size_t)N * 128 * 2);
  // layer-2 temporaries overlay h1b (dead after agg1)
  unsigned short* h2b  = h1b;                                 // N*40 bf16
  float*          a_s2 = (float*)((char*)h1b + (size_t)N * 128);  // past h2b, within h1b region
  float*          a_d2 = a_s2 + N;

  hipMemsetAsync(deg, 0, (size_t)N * 4, stream);

  int gE  = (E + TB - 1) / TB;
  int gE4 = (E + TB * 4 - 1) / (TB * 4);
  int nchunk = (N + SCAN_C - 1) / SCAN_C;

  k_histrank<<<gE4, TB, 0, stream>>>(ei, E, N, deg, rank);
  k_scan1   <<<nchunk, SCAN_T, 0, stream>>>(deg, N, excl, partials);
  k_scan2   <<<1, 64, 0, stream>>>(partials, nchunk);
  k_scan3   <<<(N + TB - 1) / TB, TB, 0, stream>>>(excl, N, partials);
  k_scatter <<<gE4, TB, 0, stream>>>(ei, E, N, excl, rank, sd);

  k_gemm1   <<<(N + 127) / 128, 256, 0, stream>>>(x, W1, h1b, N);
  k_att1    <<<(N * 8 + TB - 1) / TB, TB, 0, stream>>>(h1b, as1w, ad1w, a_s1, a_d1, N * 8);
  k_weights1<<<gE, TB, 0, stream>>>(sd, a_s1, a_d1, w1w, E);
  k_agg1    <<<(N + 3) / 4, 256, 0, stream>>>(h1b, a_s1, a_d1, sd, w1w, excl, deg, b1, out1b, N);

  k_gemm2   <<<(N + 255) / 256, 256, 0, stream>>>(out1b, W2, h2b, N);
  k_att2    <<<(N + 31) / 32, TB, 0, stream>>>(h2b, as2w, ad2w, a_s2, a_d2, N);
  k_weights2<<<gE, TB, 0, stream>>>(sd, a_s2, a_d2, w2w, E);
  k_agg2    <<<(N + 3) / 4, TB, 0, stream>>>(h2b, a_s2, a_d2, sd, w2w, excl, deg, b2, out, N);
}

// Round 6
// 394.241 us; speedup vs baseline: 1.5453x; 1.0722x over previous
//
#include <hip/hip_runtime.h>
#include <hip/hip_bf16.h>
#include <cstdint>

#define TB 256
#define SCAN_T 256
#define SCAN_C 2048

__device__ __forceinline__ float lrelu_exp(float e){
  e = e > 0.0f ? e : 0.2f * e;
  return __expf(e);
}
__device__ __forceinline__ unsigned short f2bf(float f){
  unsigned u = __float_as_uint(f);
  u = (u + 0x7fffu + ((u >> 16) & 1u)) >> 16;   // RNE
  return (unsigned short)u;
}
__device__ __forceinline__ float bf2f(unsigned short s){
  return __uint_as_float(((unsigned)s) << 16);
}
__device__ __forceinline__ float lof(unsigned u){ return __uint_as_float(u << 16); }
__device__ __forceinline__ float hif(unsigned u){ return __uint_as_float(u & 0xffff0000u); }
__device__ __forceinline__ unsigned pack2(float a, float b){
  return (unsigned)f2bf(a) | ((unsigned)f2bf(b) << 16);
}

// ---------------- CSR build (dst-indexed) ----------------
__global__ __launch_bounds__(TB) void k_histrank(const int* __restrict__ ei, int E, int n,
                                                 int* __restrict__ deg, int* __restrict__ rank){
  int b0 = blockIdx.x * (TB * 4) + threadIdx.x;
  int d[4]; int r[4]; bool ok[4];
  #pragma unroll
  for (int u = 0; u < 4; ++u){
    int e = b0 + u * TB;
    ok[u] = (e < E);
    d[u] = ok[u] ? ei[E + e] : 0;
    ok[u] = ok[u] && ((unsigned)d[u] < (unsigned)n);
  }
  #pragma unroll
  for (int u = 0; u < 4; ++u)
    if (ok[u]) r[u] = atomicAdd(&deg[d[u]], 1);
  #pragma unroll
  for (int u = 0; u < 4; ++u)
    if (ok[u]) rank[b0 + u * TB] = r[u];
}

__global__ __launch_bounds__(SCAN_T) void k_scan1(const int* __restrict__ deg, int n,
                                                  int* __restrict__ excl, int* __restrict__ partials){
  __shared__ int sums[SCAN_T];
  int t = threadIdx.x;
  int base = blockIdx.x * SCAN_C + t * 8;
  int v[8]; int s = 0;
  #pragma unroll
  for (int i = 0; i < 8; ++i){ int idx = base + i; v[i] = (idx < n) ? deg[idx] : 0; s += v[i]; }
  sums[t] = s;
  __syncthreads();
  for (int off = 1; off < SCAN_T; off <<= 1){
    int add = (t >= off) ? sums[t - off] : 0;
    __syncthreads();
    sums[t] += add;
    __syncthreads();
  }
  int run = sums[t] - s;
  if (t == SCAN_T - 1) partials[blockIdx.x] = sums[t];
  #pragma unroll
  for (int i = 0; i < 8; ++i){ int idx = base + i; if (idx < n) excl[idx] = run; run += v[i]; }
}

__global__ void k_scan2(int* partials, int nb){
  int lane = threadIdx.x;
  int orig = (lane < nb) ? partials[lane] : 0;
  int v = orig;
  for (int off = 1; off < 64; off <<= 1){
    int u = __shfl_up(v, off);
    if (lane >= off) v += u;
  }
  if (lane < nb) partials[lane] = v - orig;
}

__global__ __launch_bounds__(TB) void k_scan3(int* __restrict__ excl, int n, const int* __restrict__ partials){
  int i = blockIdx.x * TB + threadIdx.x;
  if (i < n) excl[i] += partials[i / SCAN_C];
}

__global__ __launch_bounds__(TB) void k_scatter(const int* __restrict__ ei, int E, int n,
                                                const int* __restrict__ excl, const int* __restrict__ rank,
                                                int2* __restrict__ sd){
  int b0 = blockIdx.x * (TB * 4) + threadIdx.x;
  #pragma unroll
  for (int u = 0; u < 4; ++u){
    int e = b0 + u * TB;
    if (e >= E) continue;
    int s = ei[e];
    int d = ei[E + e];
    if ((unsigned)d >= (unsigned)n || (unsigned)s >= (unsigned)n) continue;
    int pos = excl[d] + rank[e];
    sd[pos] = make_int2(s, d);
  }
}

// ---------------- GEMM1: h1b[N,128](bf16) = x[N,128] @ W1[128,128] ----------------
__global__ __launch_bounds__(256) void k_gemm1(const float* __restrict__ x, const float* __restrict__ W,
                                               unsigned short* __restrict__ hb, int n){
  __shared__ float xs[32][128];
  __shared__ float ws[32][128];
  int t = threadIdx.x;
  int ng = t & 15, cg = t >> 4;
  int node0 = blockIdx.x * 128;
  int nodeL = t >> 1, kh = t & 1;
  float acc[8][8];
  #pragma unroll
  for (int i = 0; i < 8; ++i)
    #pragma unroll
    for (int j = 0; j < 8; ++j) acc[i][j] = 0.0f;

  for (int kc = 0; kc < 4; ++kc){
    int k0 = kc * 32;
    __syncthreads();
    {
      int gn = node0 + nodeL;
      const float4* src = (const float4*)(x + (size_t)gn * 128 + k0 + kh * 16);
      #pragma unroll
      for (int u = 0; u < 4; ++u){
        float4 f = (gn < n) ? src[u] : make_float4(0.f, 0.f, 0.f, 0.f);
        int kk = kh * 16 + u * 4;
        xs[kk + 0][nodeL] = f.x; xs[kk + 1][nodeL] = f.y;
        xs[kk + 2][nodeL] = f.z; xs[kk + 3][nodeL] = f.w;
      }
      const float4* wsrc = (const float4*)(W + (size_t)k0 * 128);
      float4* wdst = (float4*)(&ws[0][0]);
      #pragma unroll
      for (int u = 0; u < 4; ++u) wdst[t + 256 * u] = wsrc[t + 256 * u];
    }
    __syncthreads();
    #pragma unroll 8
    for (int k = 0; k < 32; ++k){
      float xv[8];
      #pragma unroll
      for (int i = 0; i < 8; ++i) xv[i] = xs[k][ng + 16 * i];
      float4 w0 = *(const float4*)&ws[k][cg * 8];
      float4 w1 = *(const float4*)&ws[k][cg * 8 + 4];
      float wv[8] = {w0.x, w0.y, w0.z, w0.w, w1.x, w1.y, w1.z, w1.w};
      #pragma unroll
      for (int i = 0; i < 8; ++i)
        #pragma unroll
        for (int j = 0; j < 8; ++j) acc[i][j] = fmaf(xv[i], wv[j], acc[i][j]);
    }
  }
  #pragma unroll
  for (int i = 0; i < 8; ++i){
    int gn = node0 + ng + 16 * i;
    if (gn < n){
      uint4 o;
      o.x = pack2(acc[i][0], acc[i][1]);
      o.y = pack2(acc[i][2], acc[i][3]);
      o.z = pack2(acc[i][4], acc[i][5]);
      o.w = pack2(acc[i][6], acc[i][7]);
      *(uint4*)(hb + (size_t)gn * 128 + cg * 8) = o;
    }
  }
}

// ---------------- att1: a_s/a_d [N,8] from h1b ----------------
__global__ __launch_bounds__(TB) void k_att1(const unsigned short* __restrict__ hb, const float* __restrict__ asw,
                                             const float* __restrict__ adw,
                                             float* __restrict__ a_s, float* __restrict__ a_d, int n8){
  int idx = blockIdx.x * TB + threadIdx.x;   // node*8 + h
  if (idx >= n8) return;
  int h = idx & 7;
  uint4 lo4 = *(const uint4*)(hb + (size_t)idx * 16);
  uint4 hi4 = *(const uint4*)(hb + (size_t)idx * 16 + 8);
  float v[16];
  unsigned w_[8] = {lo4.x, lo4.y, lo4.z, lo4.w, hi4.x, hi4.y, hi4.z, hi4.w};
  #pragma unroll
  for (int u = 0; u < 8; ++u){
    v[2 * u]     = lof(w_[u]);
    v[2 * u + 1] = hif(w_[u]);
  }
  float ss = 0.f, dd = 0.f;
  #pragma unroll
  for (int u = 0; u < 16; ++u){
    ss = fmaf(v[u], asw[h * 16 + u], ss);
    dd = fmaf(v[u], adw[h * 16 + u], dd);
  }
  a_s[idx] = ss; a_d[idx] = dd;
}

// ---------------- weights1: w1w[pos][8] (bf16) + col extraction ----------------
__global__ __launch_bounds__(TB) void k_weights1(const int2* __restrict__ sd,
                                                 const float* __restrict__ a_s, const float* __restrict__ a_d,
                                                 unsigned short* __restrict__ w1w, int* __restrict__ col, int E){
  int pos = blockIdx.x * TB + threadIdx.x;
  if (pos >= E) return;
  int2 e = sd[pos];
  int s = e.x, d = e.y;
  col[pos] = s;
  float4 as0 = *(const float4*)(a_s + (size_t)s * 8);
  float4 as1 = *(const float4*)(a_s + (size_t)s * 8 + 4);
  float4 ad0 = *(const float4*)(a_d + (size_t)d * 8);
  float4 ad1 = *(const float4*)(a_d + (size_t)d * 8 + 4);
  uint4 o;
  o.x = pack2(lrelu_exp(as0.x + ad0.x), lrelu_exp(as0.y + ad0.y));
  o.y = pack2(lrelu_exp(as0.z + ad0.z), lrelu_exp(as0.w + ad0.w));
  o.z = pack2(lrelu_exp(as1.x + ad1.x), lrelu_exp(as1.y + ad1.y));
  o.w = pack2(lrelu_exp(as1.z + ad1.z), lrelu_exp(as1.w + ad1.w));
  *(uint4*)(w1w + (size_t)pos * 8) = o;
}

// ---------------- agg1: 1 wave/node, 2 edge-groups of 32 lanes (uint2 = 4 ch/lane) ----------------
__global__ __launch_bounds__(256) void k_agg1(const unsigned short* __restrict__ hb, const float* __restrict__ a_s,
    const float* __restrict__ a_d, const int* __restrict__ col, const unsigned short* __restrict__ w1w,
    const int* __restrict__ excl, const int* __restrict__ deg,
    const float* __restrict__ b1, unsigned short* __restrict__ out1b, int n){
  int tl = threadIdx.x & 63;
  int node = blockIdx.x * 4 + (threadIdx.x >> 6);
  if (node >= n) return;
  int g  = tl >> 5;          // edge group 0/1
  int il = tl & 31;          // channels [4il, 4il+4)
  int h  = il >> 2;
  float acc0 = 0.f, acc1 = 0.f, acc2 = 0.f, acc3 = 0.f, denom = 0.f;
  if (g == 0){
    float wSelf = lrelu_exp(a_s[(size_t)node * 8 + h] + a_d[(size_t)node * 8 + h]);
    uint2 hv = *(const uint2*)(hb + (size_t)node * 128 + il * 4);
    acc0 = wSelf * lof(hv.x); acc1 = wSelf * hif(hv.x);
    acc2 = wSelf * lof(hv.y); acc3 = wSelf * hif(hv.y);
    denom = wSelf;
  }
  int pp = excl[node];
  int end = pp + deg[node];
  for (; pp + 16 <= end; pp += 16){
    int s[8]; float w[8]; uint2 v[8];
    #pragma unroll
    for (int u = 0; u < 8; ++u) s[u] = col[pp + 2 * u + g];
    #pragma unroll
    for (int u = 0; u < 8; ++u) w[u] = bf2f(w1w[(size_t)(pp + 2 * u + g) * 8 + h]);
    #pragma unroll
    for (int u = 0; u < 8; ++u) v[u] = *(const uint2*)(hb + (size_t)s[u] * 128 + il * 4);
    #pragma unroll
    for (int u = 0; u < 8; ++u){
      acc0 = fmaf(w[u], lof(v[u].x), acc0);
      acc1 = fmaf(w[u], hif(v[u].x), acc1);
      acc2 = fmaf(w[u], lof(v[u].y), acc2);
      acc3 = fmaf(w[u], hif(v[u].y), acc3);
      denom += w[u];
    }
  }
  for (; pp + 2 <= end; pp += 2){
    int e = pp + g;
    int s0 = col[e];
    float w0 = bf2f(w1w[(size_t)e * 8 + h]);
    uint2 v0 = *(const uint2*)(hb + (size_t)s0 * 128 + il * 4);
    acc0 = fmaf(w0, lof(v0.x), acc0);
    acc1 = fmaf(w0, hif(v0.x), acc1);
    acc2 = fmaf(w0, lof(v0.y), acc2);
    acc3 = fmaf(w0, hif(v0.y), acc3);
    denom += w0;
  }
  if (pp < end && g == 0){
    int s0 = col[pp];
    float w0 = bf2f(w1w[(size_t)pp * 8 + h]);
    uint2 v0 = *(const uint2*)(hb + (size_t)s0 * 128 + il * 4);
    acc0 = fmaf(w0, lof(v0.x), acc0);
    acc1 = fmaf(w0, hif(v0.x), acc1);
    acc2 = fmaf(w0, lof(v0.y), acc2);
    acc3 = fmaf(w0, hif(v0.y), acc3);
    denom += w0;
  }
  acc0 += __shfl_xor(acc0, 32); acc1 += __shfl_xor(acc1, 32);
  acc2 += __shfl_xor(acc2, 32); acc3 += __shfl_xor(acc3, 32);
  denom += __shfl_xor(denom, 32);
  float inv = 1.0f / denom;
  float4 bb = *(const float4*)(b1 + il * 4);
  float o0 = fmaf(acc0, inv, bb.x); o0 = o0 > 0.f ? o0 : 0.f;
  float o1 = fmaf(acc1, inv, bb.y); o1 = o1 > 0.f ? o1 : 0.f;
  float o2 = fmaf(acc2, inv, bb.z); o2 = o2 > 0.f ? o2 : 0.f;
  float o3 = fmaf(acc3, inv, bb.w); o3 = o3 > 0.f ? o3 : 0.f;
  if (g == 0){
    uint2 o; o.x = pack2(o0, o1); o.y = pack2(o2, o3);
    *(uint2*)(out1b + (size_t)node * 128 + il * 4) = o;
  }
}

// ---------------- GEMM2: h2b[N,64-padded](bf16) = out1b[N,128](bf16) @ W2[128,40] ----------------
__global__ __launch_bounds__(256) void k_gemm2(const unsigned short* __restrict__ ab, const float* __restrict__ W2,
                                               unsigned short* __restrict__ h2b, int n){
  __shared__ float xs[32][256];
  __shared__ float ws[128][40];
  int t = threadIdx.x;
  for (int i = t; i < 128 * 40; i += 256) (&ws[0][0])[i] = W2[i];
  int ng = t & 63, cg = t >> 6;
  int node0 = blockIdx.x * 256;
  float acc[4][10];
  #pragma unroll
  for (int i = 0; i < 4; ++i)
    #pragma unroll
    for (int j = 0; j < 10; ++j) acc[i][j] = 0.0f;

  for (int kc = 0; kc < 4; ++kc){
    int k0 = kc * 32;
    __syncthreads();
    {
      int gn = node0 + t;
      uint4 q[2];
      if (gn < n){
        const uint4* src = (const uint4*)(ab + (size_t)gn * 128 + k0);
        q[0] = src[0]; q[1] = src[1];
      } else {
        q[0] = make_uint4(0,0,0,0); q[1] = make_uint4(0,0,0,0);
      }
      #pragma unroll
      for (int u = 0; u < 2; ++u){
        unsigned w4[4] = {q[u].x, q[u].y, q[u].z, q[u].w};
        #pragma unroll
        for (int j = 0; j < 4; ++j){
          int kk = u * 8 + j * 2;
          xs[kk][t]     = lof(w4[j]);
          xs[kk + 1][t] = hif(w4[j]);
        }
      }
      uint4 r[2];
      if (gn < n){
        const uint4* src = (const uint4*)(ab + (size_t)gn * 128 + k0 + 16);
        r[0] = src[0]; r[1] = src[1];
      } else {
        r[0] = make_uint4(0,0,0,0); r[1] = make_uint4(0,0,0,0);
      }
      #pragma unroll
      for (int u = 0; u < 2; ++u){
        unsigned w4[4] = {r[u].x, r[u].y, r[u].z, r[u].w};
        #pragma unroll
        for (int j = 0; j < 4; ++j){
          int kk = 16 + u * 8 + j * 2;
          xs[kk][t]     = lof(w4[j]);
          xs[kk + 1][t] = hif(w4[j]);
        }
      }
    }
    __syncthreads();
    #pragma unroll 4
    for (int k = 0; k < 32; ++k){
      float xv[4];
      #pragma unroll
      for (int i = 0; i < 4; ++i) xv[i] = xs[k][ng + 64 * i];
      float wv[10];
      #pragma unroll
      for (int j = 0; j < 10; ++j) wv[j] = ws[k0 + k][cg * 10 + j];
      #pragma unroll
      for (int i = 0; i < 4; ++i)
        #pragma unroll
        for (int j = 0; j < 10; ++j) acc[i][j] = fmaf(xv[i], wv[j], acc[i][j]);
    }
  }
  #pragma unroll
  for (int i = 0; i < 4; ++i){
    int gn = node0 + ng + 64 * i;
    if (gn < n){
      unsigned pk[5];
      #pragma unroll
      for (int j = 0; j < 5; ++j) pk[j] = pack2(acc[i][2 * j], acc[i][2 * j + 1]);
      unsigned* dst = (unsigned*)h2b + (size_t)gn * 32 + cg * 5;   // padded stride 64 ushorts
      #pragma unroll
      for (int j = 0; j < 5; ++j) dst[j] = pk[j];
    }
  }
}

// ---------------- att2: a_s/a_d [N] from h2b (stride 64) ----------------
__global__ __launch_bounds__(TB) void k_att2(const unsigned short* __restrict__ h2b, const float* __restrict__ asw,
                                             const float* __restrict__ adw,
                                             float* __restrict__ a_s, float* __restrict__ a_d, int n){
  int t = threadIdx.x;
  int node = blockIdx.x * 32 + (t >> 3);
  int sub = t & 7;
  if (node >= n) return;
  float ss = 0.f, dd = 0.f;
  for (int j = sub; j < 40; j += 8){
    float v = bf2f(h2b[(size_t)node * 64 + j]);
    ss = fmaf(v, asw[j], ss);
    dd = fmaf(v, adw[j], dd);
  }
  #pragma unroll
  for (int off = 1; off < 8; off <<= 1){
    ss += __shfl_xor(ss, off);
    dd += __shfl_xor(dd, off);
  }
  if (sub == 0){ a_s[node] = ss; a_d[node] = dd; }
}

// ---------------- weights2: w2w[pos] (bf16) ----------------
__global__ __launch_bounds__(TB) void k_weights2(const int2* __restrict__ sd,
                                                 const float* __restrict__ a_s, const float* __restrict__ a_d,
                                                 unsigned short* __restrict__ w2w, int E){
  int pos = blockIdx.x * TB + threadIdx.x;
  if (pos >= E) return;
  int2 e = sd[pos];
  w2w[pos] = f2bf(lrelu_exp(a_s[e.x] + a_d[e.y]));
}

// ---------------- agg2 + log_softmax, 2 edge-groups of 32 lanes (uint = 2 ch/lane) ----------------
__global__ __launch_bounds__(256) void k_agg2(const unsigned short* __restrict__ h2b, const float* __restrict__ a_s,
    const float* __restrict__ a_d, const int* __restrict__ col, const unsigned short* __restrict__ w2w,
    const int* __restrict__ excl, const int* __restrict__ deg,
    const float* __restrict__ b2, float* __restrict__ out, int n){
  int tl = threadIdx.x & 63;
  int node = blockIdx.x * 4 + (threadIdx.x >> 6);
  if (node >= n) return;
  int g = tl >> 5, il = tl & 31;
  bool act = il < 20;                       // channels 2il, 2il+1 (< 40)
  const unsigned* h2u = (const unsigned*)h2b;   // rows of 32 uints (64 ushorts, padded)
  float acc0 = 0.f, acc1 = 0.f, denom = 0.f;
  if (g == 0){
    float wSelf = lrelu_exp(a_s[node] + a_d[node]);
    unsigned hv = h2u[(size_t)node * 32 + il];
    acc0 = wSelf * lof(hv); acc1 = wSelf * hif(hv);
    denom = wSelf;
  }
  int pp = excl[node];
  int end = pp + deg[node];
  for (; pp + 16 <= end; pp += 16){
    int s[8]; float w[8]; unsigned v[8];
    #pragma unroll
    for (int u = 0; u < 8; ++u) s[u] = col[pp + 2 * u + g];
    #pragma unroll
    for (int u = 0; u < 8; ++u) w[u] = bf2f(w2w[pp + 2 * u + g]);
    #pragma unroll
    for (int u = 0; u < 8; ++u) v[u] = h2u[(size_t)s[u] * 32 + il];
    #pragma unroll
    for (int u = 0; u < 8; ++u){
      acc0 = fmaf(w[u], lof(v[u]), acc0);
      acc1 = fmaf(w[u], hif(v[u]), acc1);
      denom += w[u];
    }
  }
  for (; pp + 2 <= end; pp += 2){
    int e = pp + g;
    int s0 = col[e];
    float w0 = bf2f(w2w[e]);
    unsigned v0 = h2u[(size_t)s0 * 32 + il];
    acc0 = fmaf(w0, lof(v0), acc0);
    acc1 = fmaf(w0, hif(v0), acc1);
    denom += w0;
  }
  if (pp < end && g == 0){
    int s0 = col[pp];
    float w0 = bf2f(w2w[pp]);
    unsigned v0 = h2u[(size_t)s0 * 32 + il];
    acc0 = fmaf(w0, lof(v0), acc0);
    acc1 = fmaf(w0, hif(v0), acc1);
    denom += w0;
  }
  acc0 += __shfl_xor(acc0, 32);
  acc1 += __shfl_xor(acc1, 32);
  denom += __shfl_xor(denom, 32);
  float inv = 1.0f / denom;
  float2 bb = act ? *(const float2*)(b2 + il * 2) : make_float2(0.f, 0.f);
  float vv0 = act ? fmaf(acc0, inv, bb.x) : -1e30f;
  float vv1 = act ? fmaf(acc1, inv, bb.y) : -1e30f;
  float m = fmaxf(vv0, vv1);
  #pragma unroll
  for (int off = 16; off >= 1; off >>= 1) m = fmaxf(m, __shfl_xor(m, off));
  float S = act ? (__expf(vv0 - m) + __expf(vv1 - m)) : 0.f;
  #pragma unroll
  for (int off = 16; off >= 1; off >>= 1) S += __shfl_xor(S, off);
  float ls = __logf(S);
  if (tl < 20){
    float2 o = make_float2(vv0 - m - ls, vv1 - m - ls);
    *(float2*)(out + (size_t)node * 40 + il * 2) = o;
  }
}

extern "C" void kernel_launch(void* const* d_in, const int* in_sizes, int n_in,
                              void* d_out, int out_size, void* d_ws, size_t ws_size,
                              hipStream_t stream){
  const float* x    = (const float*)d_in[0];
  const int*   ei   = (const int*)d_in[1];          // int32 (jax x64 disabled)
  const float* W1   = (const float*)d_in[2];
  const float* as1w = (const float*)d_in[3];
  const float* ad1w = (const float*)d_in[4];
  const float* b1   = (const float*)d_in[5];
  const float* W2   = (const float*)d_in[6];
  const float* as2w = (const float*)d_in[7];
  const float* ad2w = (const float*)d_in[8];
  const float* b2   = (const float*)d_in[9];
  float* out = (float*)d_out;
  const int N = in_sizes[0] / 128;
  const int E = in_sizes[1] / 2;

  char* p = (char*)d_ws;
  auto alloc = [&](size_t bytes) -> void* {
    void* r = (void*)p;
    p += (bytes + 511) & ~(size_t)511;
    return r;
  };
  int*            deg      = (int*)           alloc((size_t)N * 4);
  int*            excl     = (int*)           alloc((size_t)N * 4);
  int*            partials = (int*)           alloc(64 * 4);
  int*            rank     = (int*)           alloc((size_t)E * 4);
  int2*           sd       = (int2*)          alloc((size_t)E * 8);
  int*            col      = (int*)           alloc((size_t)E * 4);
  float*          a_s1     = (float*)         alloc((size_t)N * 8 * 4);
  float*          a_d1     = (float*)         alloc((size_t)N * 8 * 4);
  unsigned short* w1w      = (unsigned short*)alloc((size_t)E * 8 * 2);
  unsigned short* w2w      = (unsigned short*)alloc((size_t)E * 2);
  unsigned short* out1b    = (unsigned short*)alloc((size_t)N * 128 * 2);
  unsigned short* h1b      = (unsigned short*)alloc((size_t)N * 128 * 2);
  // layer-2 temporaries overlay h1b (dead after agg1): h2b = N*64 ushorts (padded)
  unsigned short* h2b  = h1b;
  float*          a_s2 = (float*)((char*)h1b + (size_t)N * 128);  // right after padded h2b
  float*          a_d2 = a_s2 + N;

  hipMemsetAsync(deg, 0, (size_t)N * 4, stream);

  int gE  = (E + TB - 1) / TB;
  int gE4 = (E + TB * 4 - 1) / (TB * 4);
  int nchunk = (N + SCAN_C - 1) / SCAN_C;

  k_histrank<<<gE4, TB, 0, stream>>>(ei, E, N, deg, rank);
  k_scan1   <<<nchunk, SCAN_T, 0, stream>>>(deg, N, excl, partials);
  k_scan2   <<<1, 64, 0, stream>>>(partials, nchunk);
  k_scan3   <<<(N + TB - 1) / TB, TB, 0, stream>>>(excl, N, partials);
  k_scatter <<<gE4, TB, 0, stream>>>(ei, E, N, excl, rank, sd);

  k_gemm1   <<<(N + 127) / 128, 256, 0, stream>>>(x, W1, h1b, N);
  k_att1    <<<(N * 8 + TB - 1) / TB, TB, 0, stream>>>(h1b, as1w, ad1w, a_s1, a_d1, N * 8);
  k_weights1<<<gE, TB, 0, stream>>>(sd, a_s1, a_d1, w1w, col, E);
  k_agg1    <<<(N + 3) / 4, 256, 0, stream>>>(h1b, a_s1, a_d1, col, w1w, excl, deg, b1, out1b, N);

  k_gemm2   <<<(N + 255) / 256, 256, 0, stream>>>(out1b, W2, h2b, N);
  k_att2    <<<(N + 31) / 32, TB, 0, stream>>>(h2b, as2w, ad2w, a_s2, a_d2, N);
  k_weights2<<<gE, TB, 0, stream>>>(sd, a_s2, a_d2, w2w, E);
  k_agg2    <<<(N + 3) / 4, 256, 0, stream>>>(h2b, a_s2, a_d2, col, w2w, excl, deg, b2, out, N);
}

// Round 7
// 379.320 us; speedup vs baseline: 1.6061x; 1.0393x over previous
//
#include <hip/hip_runtime.h>
#include <hip/hip_bf16.h>
#include <cstdint>

#define TB 256
#define SCAN_T 256
#define SCAN_C 2048

__device__ __forceinline__ float lrelu_exp(float e){
  e = e > 0.0f ? e : 0.2f * e;
  return __expf(e);
}
__device__ __forceinline__ unsigned short f2bf(float f){
  unsigned u = __float_as_uint(f);
  u = (u + 0x7fffu + ((u >> 16) & 1u)) >> 16;   // RNE
  return (unsigned short)u;
}
__device__ __forceinline__ float bf2f(unsigned short s){
  return __uint_as_float(((unsigned)s) << 16);
}
__device__ __forceinline__ float lof(unsigned u){ return __uint_as_float(u << 16); }
__device__ __forceinline__ float hif(unsigned u){ return __uint_as_float(u & 0xffff0000u); }
__device__ __forceinline__ unsigned pack2(float a, float b){
  return (unsigned)f2bf(a) | ((unsigned)f2bf(b) << 16);
}

// ---------------- CSR build (dst-indexed) ----------------
// histogram + rank capture, 8 edges/thread for atomic-latency hiding
__global__ __launch_bounds__(TB) void k_histrank(const int* __restrict__ ei, int E, int n,
                                                 int* __restrict__ deg, int* __restrict__ rank){
  int b0 = blockIdx.x * (TB * 8) + threadIdx.x;
  int d[8]; int r[8]; bool ok[8];
  #pragma unroll
  for (int u = 0; u < 8; ++u){
    int e = b0 + u * TB;
    ok[u] = (e < E);
    d[u] = ok[u] ? ei[E + e] : 0;
    ok[u] = ok[u] && ((unsigned)d[u] < (unsigned)n);
  }
  #pragma unroll
  for (int u = 0; u < 8; ++u)
    if (ok[u]) r[u] = atomicAdd(&deg[d[u]], 1);
  #pragma unroll
  for (int u = 0; u < 8; ++u)
    if (ok[u]) rank[b0 + u * TB] = r[u];
}

__global__ __launch_bounds__(SCAN_T) void k_scan1(const int* __restrict__ deg, int n,
                                                  int* __restrict__ excl, int* __restrict__ partials){
  __shared__ int sums[SCAN_T];
  int t = threadIdx.x;
  int base = blockIdx.x * SCAN_C + t * 8;
  int v[8]; int s = 0;
  #pragma unroll
  for (int i = 0; i < 8; ++i){ int idx = base + i; v[i] = (idx < n) ? deg[idx] : 0; s += v[i]; }
  sums[t] = s;
  __syncthreads();
  for (int off = 1; off < SCAN_T; off <<= 1){
    int add = (t >= off) ? sums[t - off] : 0;
    __syncthreads();
    sums[t] += add;
    __syncthreads();
  }
  int run = sums[t] - s;
  if (t == SCAN_T - 1) partials[blockIdx.x] = sums[t];
  #pragma unroll
  for (int i = 0; i < 8; ++i){ int idx = base + i; if (idx < n) excl[idx] = run; run += v[i]; }
}

__global__ void k_scan2(int* partials, int nb){
  int lane = threadIdx.x;
  int orig = (lane < nb) ? partials[lane] : 0;
  int v = orig;
  for (int off = 1; off < 64; off <<= 1){
    int u = __shfl_up(v, off);
    if (lane >= off) v += u;
  }
  if (lane < nb) partials[lane] = v - orig;
}

__global__ __launch_bounds__(TB) void k_scan3(int* __restrict__ excl, int n, const int* __restrict__ partials){
  int i = blockIdx.x * TB + threadIdx.x;
  if (i < n) excl[i] += partials[i / SCAN_C];
}

// scatter without atomics: col[excl[d] + rank[e]] = s  (4 B random store)
__global__ __launch_bounds__(TB) void k_scatter(const int* __restrict__ ei, int E, int n,
                                                const int* __restrict__ excl, const int* __restrict__ rank,
                                                int* __restrict__ col){
  int b0 = blockIdx.x * (TB * 4) + threadIdx.x;
  #pragma unroll
  for (int u = 0; u < 4; ++u){
    int e = b0 + u * TB;
    if (e >= E) continue;
    int s = ei[e];
    int d = ei[E + e];
    if ((unsigned)d >= (unsigned)n || (unsigned)s >= (unsigned)n) continue;
    int pos = excl[d] + rank[e];
    col[pos] = s;
  }
}

// ---------------- GEMM1: h1b[N,128](bf16) = x[N,128] @ W1[128,128] ----------------
__global__ __launch_bounds__(256) void k_gemm1(const float* __restrict__ x, const float* __restrict__ W,
                                               unsigned short* __restrict__ hb, int n){
  __shared__ float xs[32][128];
  __shared__ float ws[32][128];
  int t = threadIdx.x;
  int ng = t & 15, cg = t >> 4;
  int node0 = blockIdx.x * 128;
  int nodeL = t >> 1, kh = t & 1;
  float acc[8][8];
  #pragma unroll
  for (int i = 0; i < 8; ++i)
    #pragma unroll
    for (int j = 0; j < 8; ++j) acc[i][j] = 0.0f;

  for (int kc = 0; kc < 4; ++kc){
    int k0 = kc * 32;
    __syncthreads();
    {
      int gn = node0 + nodeL;
      const float4* src = (const float4*)(x + (size_t)gn * 128 + k0 + kh * 16);
      #pragma unroll
      for (int u = 0; u < 4; ++u){
        float4 f = (gn < n) ? src[u] : make_float4(0.f, 0.f, 0.f, 0.f);
        int kk = kh * 16 + u * 4;
        xs[kk + 0][nodeL] = f.x; xs[kk + 1][nodeL] = f.y;
        xs[kk + 2][nodeL] = f.z; xs[kk + 3][nodeL] = f.w;
      }
      const float4* wsrc = (const float4*)(W + (size_t)k0 * 128);
      float4* wdst = (float4*)(&ws[0][0]);
      #pragma unroll
      for (int u = 0; u < 4; ++u) wdst[t + 256 * u] = wsrc[t + 256 * u];
    }
    __syncthreads();
    #pragma unroll 8
    for (int k = 0; k < 32; ++k){
      float xv[8];
      #pragma unroll
      for (int i = 0; i < 8; ++i) xv[i] = xs[k][ng + 16 * i];
      float4 w0 = *(const float4*)&ws[k][cg * 8];
      float4 w1 = *(const float4*)&ws[k][cg * 8 + 4];
      float wv[8] = {w0.x, w0.y, w0.z, w0.w, w1.x, w1.y, w1.z, w1.w};
      #pragma unroll
      for (int i = 0; i < 8; ++i)
        #pragma unroll
        for (int j = 0; j < 8; ++j) acc[i][j] = fmaf(xv[i], wv[j], acc[i][j]);
    }
  }
  #pragma unroll
  for (int i = 0; i < 8; ++i){
    int gn = node0 + ng + 16 * i;
    if (gn < n){
      uint4 o;
      o.x = pack2(acc[i][0], acc[i][1]);
      o.y = pack2(acc[i][2], acc[i][3]);
      o.z = pack2(acc[i][4], acc[i][5]);
      o.w = pack2(acc[i][6], acc[i][7]);
      *(uint4*)(hb + (size_t)gn * 128 + cg * 8) = o;
    }
  }
}

// ---------------- att1: a_s/a_d [N,8] from h1b ----------------
__global__ __launch_bounds__(TB) void k_att1(const unsigned short* __restrict__ hb, const float* __restrict__ asw,
                                             const float* __restrict__ adw,
                                             float* __restrict__ a_s, float* __restrict__ a_d, int n8){
  int idx = blockIdx.x * TB + threadIdx.x;   // node*8 + h
  if (idx >= n8) return;
  int h = idx & 7;
  uint4 lo4 = *(const uint4*)(hb + (size_t)idx * 16);
  uint4 hi4 = *(const uint4*)(hb + (size_t)idx * 16 + 8);
  float v[16];
  unsigned w_[8] = {lo4.x, lo4.y, lo4.z, lo4.w, hi4.x, hi4.y, hi4.z, hi4.w};
  #pragma unroll
  for (int u = 0; u < 8; ++u){
    v[2 * u]     = lof(w_[u]);
    v[2 * u + 1] = hif(w_[u]);
  }
  float ss = 0.f, dd = 0.f;
  #pragma unroll
  for (int u = 0; u < 16; ++u){
    ss = fmaf(v[u], asw[h * 16 + u], ss);
    dd = fmaf(v[u], adw[h * 16 + u], dd);
  }
  a_s[idx] = ss; a_d[idx] = dd;
}

// ---------------- agg1: fused weights, 2 edge-groups of 32 lanes (uint2 = 4 ch/lane) ----------------
__global__ __launch_bounds__(256) void k_agg1(const unsigned short* __restrict__ hb, const float* __restrict__ a_s,
    const float* __restrict__ a_d, const int* __restrict__ col,
    const int* __restrict__ excl, const int* __restrict__ deg,
    const float* __restrict__ b1, unsigned short* __restrict__ out1b, int n){
  int tl = threadIdx.x & 63;
  int node = blockIdx.x * 4 + (threadIdx.x >> 6);
  if (node >= n) return;
  int g  = tl >> 5;          // edge group 0/1
  int il = tl & 31;          // channels [4il, 4il+4)
  int h  = il >> 2;
  float adn = a_d[(size_t)node * 8 + h];        // loop-invariant: dst == node
  float acc0 = 0.f, acc1 = 0.f, acc2 = 0.f, acc3 = 0.f, denom = 0.f;
  if (g == 0){
    float wSelf = lrelu_exp(a_s[(size_t)node * 8 + h] + adn);
    uint2 hv = *(const uint2*)(hb + (size_t)node * 128 + il * 4);
    acc0 = wSelf * lof(hv.x); acc1 = wSelf * hif(hv.x);
    acc2 = wSelf * lof(hv.y); acc3 = wSelf * hif(hv.y);
    denom = wSelf;
  }
  int pp = excl[node];
  int end = pp + deg[node];
  for (; pp + 16 <= end; pp += 16){
    int s[8]; float as[8]; uint2 v[8];
    #pragma unroll
    for (int u = 0; u < 8; ++u) s[u] = col[pp + 2 * u + g];
    #pragma unroll
    for (int u = 0; u < 8; ++u) as[u] = a_s[(size_t)s[u] * 8 + h];
    #pragma unroll
    for (int u = 0; u < 8; ++u) v[u] = *(const uint2*)(hb + (size_t)s[u] * 128 + il * 4);
    #pragma unroll
    for (int u = 0; u < 8; ++u){
      float w = lrelu_exp(as[u] + adn);
      acc0 = fmaf(w, lof(v[u].x), acc0);
      acc1 = fmaf(w, hif(v[u].x), acc1);
      acc2 = fmaf(w, lof(v[u].y), acc2);
      acc3 = fmaf(w, hif(v[u].y), acc3);
      denom += w;
    }
  }
  for (; pp + 2 <= end; pp += 2){
    int e = pp + g;
    int s0 = col[e];
    float w = lrelu_exp(a_s[(size_t)s0 * 8 + h] + adn);
    uint2 v0 = *(const uint2*)(hb + (size_t)s0 * 128 + il * 4);
    acc0 = fmaf(w, lof(v0.x), acc0);
    acc1 = fmaf(w, hif(v0.x), acc1);
    acc2 = fmaf(w, lof(v0.y), acc2);
    acc3 = fmaf(w, hif(v0.y), acc3);
    denom += w;
  }
  if (pp < end && g == 0){
    int s0 = col[pp];
    float w = lrelu_exp(a_s[(size_t)s0 * 8 + h] + adn);
    uint2 v0 = *(const uint2*)(hb + (size_t)s0 * 128 + il * 4);
    acc0 = fmaf(w, lof(v0.x), acc0);
    acc1 = fmaf(w, hif(v0.x), acc1);
    acc2 = fmaf(w, lof(v0.y), acc2);
    acc3 = fmaf(w, hif(v0.y), acc3);
    denom += w;
  }
  acc0 += __shfl_xor(acc0, 32); acc1 += __shfl_xor(acc1, 32);
  acc2 += __shfl_xor(acc2, 32); acc3 += __shfl_xor(acc3, 32);
  denom += __shfl_xor(denom, 32);
  float inv = 1.0f / denom;
  float4 bb = *(const float4*)(b1 + il * 4);
  float o0 = fmaf(acc0, inv, bb.x); o0 = o0 > 0.f ? o0 : 0.f;
  float o1 = fmaf(acc1, inv, bb.y); o1 = o1 > 0.f ? o1 : 0.f;
  float o2 = fmaf(acc2, inv, bb.z); o2 = o2 > 0.f ? o2 : 0.f;
  float o3 = fmaf(acc3, inv, bb.w); o3 = o3 > 0.f ? o3 : 0.f;
  if (g == 0){
    uint2 o; o.x = pack2(o0, o1); o.y = pack2(o2, o3);
    *(uint2*)(out1b + (size_t)node * 128 + il * 4) = o;
  }
}

// ---------------- GEMM2: h2b[N,64-padded](bf16) = out1b[N,128](bf16) @ W2[128,40] ----------------
__global__ __launch_bounds__(256) void k_gemm2(const unsigned short* __restrict__ ab, const float* __restrict__ W2,
                                               unsigned short* __restrict__ h2b, int n){
  __shared__ float xs[32][256];
  __shared__ float ws[128][40];
  int t = threadIdx.x;
  for (int i = t; i < 128 * 40; i += 256) (&ws[0][0])[i] = W2[i];
  int ng = t & 63, cg = t >> 6;
  int node0 = blockIdx.x * 256;
  float acc[4][10];
  #pragma unroll
  for (int i = 0; i < 4; ++i)
    #pragma unroll
    for (int j = 0; j < 10; ++j) acc[i][j] = 0.0f;

  for (int kc = 0; kc < 4; ++kc){
    int k0 = kc * 32;
    __syncthreads();
    {
      int gn = node0 + t;
      uint4 q[2];
      if (gn < n){
        const uint4* src = (const uint4*)(ab + (size_t)gn * 128 + k0);
        q[0] = src[0]; q[1] = src[1];
      } else {
        q[0] = make_uint4(0,0,0,0); q[1] = make_uint4(0,0,0,0);
      }
      #pragma unroll
      for (int u = 0; u < 2; ++u){
        unsigned w4[4] = {q[u].x, q[u].y, q[u].z, q[u].w};
        #pragma unroll
        for (int j = 0; j < 4; ++j){
          int kk = u * 8 + j * 2;
          xs[kk][t]     = lof(w4[j]);
          xs[kk + 1][t] = hif(w4[j]);
        }
      }
      uint4 r[2];
      if (gn < n){
        const uint4* src = (const uint4*)(ab + (size_t)gn * 128 + k0 + 16);
        r[0] = src[0]; r[1] = src[1];
      } else {
        r[0] = make_uint4(0,0,0,0); r[1] = make_uint4(0,0,0,0);
      }
      #pragma unroll
      for (int u = 0; u < 2; ++u){
        unsigned w4[4] = {r[u].x, r[u].y, r[u].z, r[u].w};
        #pragma unroll
        for (int j = 0; j < 4; ++j){
          int kk = 16 + u * 8 + j * 2;
          xs[kk][t]     = lof(w4[j]);
          xs[kk + 1][t] = hif(w4[j]);
        }
      }
    }
    __syncthreads();
    #pragma unroll 4
    for (int k = 0; k < 32; ++k){
      float xv[4];
      #pragma unroll
      for (int i = 0; i < 4; ++i) xv[i] = xs[k][ng + 64 * i];
      float wv[10];
      #pragma unroll
      for (int j = 0; j < 10; ++j) wv[j] = ws[k0 + k][cg * 10 + j];
      #pragma unroll
      for (int i = 0; i < 4; ++i)
        #pragma unroll
        for (int j = 0; j < 10; ++j) acc[i][j] = fmaf(xv[i], wv[j], acc[i][j]);
    }
  }
  #pragma unroll
  for (int i = 0; i < 4; ++i){
    int gn = node0 + ng + 64 * i;
    if (gn < n){
      unsigned pk[5];
      #pragma unroll
      for (int j = 0; j < 5; ++j) pk[j] = pack2(acc[i][2 * j], acc[i][2 * j + 1]);
      unsigned* dst = (unsigned*)h2b + (size_t)gn * 32 + cg * 5;   // padded stride 64 ushorts
      #pragma unroll
      for (int j = 0; j < 5; ++j) dst[j] = pk[j];
    }
  }
}

// ---------------- att2: a_s/a_d [N] from h2b (stride 64) ----------------
__global__ __launch_bounds__(TB) void k_att2(const unsigned short* __restrict__ h2b, const float* __restrict__ asw,
                                             const float* __restrict__ adw,
                                             float* __restrict__ a_s, float* __restrict__ a_d, int n){
  int t = threadIdx.x;
  int node = blockIdx.x * 32 + (t >> 3);
  int sub = t & 7;
  if (node >= n) return;
  float ss = 0.f, dd = 0.f;
  for (int j = sub; j < 40; j += 8){
    float v = bf2f(h2b[(size_t)node * 64 + j]);
    ss = fmaf(v, asw[j], ss);
    dd = fmaf(v, adw[j], dd);
  }
  #pragma unroll
  for (int off = 1; off < 8; off <<= 1){
    ss += __shfl_xor(ss, off);
    dd += __shfl_xor(dd, off);
  }
  if (sub == 0){ a_s[node] = ss; a_d[node] = dd; }
}

// ---------------- agg2 + log_softmax: fused weights, 2 edge-groups (uint = 2 ch/lane) ----------------
__global__ __launch_bounds__(256) void k_agg2(const unsigned short* __restrict__ h2b, const float* __restrict__ a_s,
    const float* __restrict__ a_d, const int* __restrict__ col,
    const int* __restrict__ excl, const int* __restrict__ deg,
    const float* __restrict__ b2, float* __restrict__ out, int n){
  int tl = threadIdx.x & 63;
  int node = blockIdx.x * 4 + (threadIdx.x >> 6);
  if (node >= n) return;
  int g = tl >> 5, il = tl & 31;
  bool act = il < 20;                       // channels 2il, 2il+1 (< 40)
  const unsigned* h2u = (const unsigned*)h2b;   // rows of 32 uints (64 ushorts, padded)
  float adn = a_d[node];                    // loop-invariant: dst == node
  float acc0 = 0.f, acc1 = 0.f, denom = 0.f;
  if (g == 0){
    float wSelf = lrelu_exp(a_s[node] + adn);
    unsigned hv = h2u[(size_t)node * 32 + il];
    acc0 = wSelf * lof(hv); acc1 = wSelf * hif(hv);
    denom = wSelf;
  }
  int pp = excl[node];
  int end = pp + deg[node];
  for (; pp + 16 <= end; pp += 16){
    int s[8]; float as[8]; unsigned v[8];
    #pragma unroll
    for (int u = 0; u < 8; ++u) s[u] = col[pp + 2 * u + g];
    #pragma unroll
    for (int u = 0; u < 8; ++u) as[u] = a_s[s[u]];
    #pragma unroll
    for (int u = 0; u < 8; ++u) v[u] = h2u[(size_t)s[u] * 32 + il];
    #pragma unroll
    for (int u = 0; u < 8; ++u){
      float w = lrelu_exp(as[u] + adn);
      acc0 = fmaf(w, lof(v[u]), acc0);
      acc1 = fmaf(w, hif(v[u]), acc1);
      denom += w;
    }
  }
  for (; pp + 2 <= end; pp += 2){
    int e = pp + g;
    int s0 = col[e];
    float w = lrelu_exp(a_s[s0] + adn);
    unsigned v0 = h2u[(size_t)s0 * 32 + il];
    acc0 = fmaf(w, lof(v0), acc0);
    acc1 = fmaf(w, hif(v0), acc1);
    denom += w;
  }
  if (pp < end && g == 0){
    int s0 = col[pp];
    float w = lrelu_exp(a_s[s0] + adn);
    unsigned v0 = h2u[(size_t)s0 * 32 + il];
    acc0 = fmaf(w, lof(v0), acc0);
    acc1 = fmaf(w, hif(v0), acc1);
    denom += w;
  }
  acc0 += __shfl_xor(acc0, 32);
  acc1 += __shfl_xor(acc1, 32);
  denom += __shfl_xor(denom, 32);
  float inv = 1.0f / denom;
  float2 bb = act ? *(const float2*)(b2 + il * 2) : make_float2(0.f, 0.f);
  float vv0 = act ? fmaf(acc0, inv, bb.x) : -1e30f;
  float vv1 = act ? fmaf(acc1, inv, bb.y) : -1e30f;
  float m = fmaxf(vv0, vv1);
  #pragma unroll
  for (int off = 16; off >= 1; off >>= 1) m = fmaxf(m, __shfl_xor(m, off));
  float S = act ? (__expf(vv0 - m) + __expf(vv1 - m)) : 0.f;
  #pragma unroll
  for (int off = 16; off >= 1; off >>= 1) S += __shfl_xor(S, off);
  float ls = __logf(S);
  if (tl < 20){
    float2 o = make_float2(vv0 - m - ls, vv1 - m - ls);
    *(float2*)(out + (size_t)node * 40 + il * 2) = o;
  }
}

extern "C" void kernel_launch(void* const* d_in, const int* in_sizes, int n_in,
                              void* d_out, int out_size, void* d_ws, size_t ws_size,
                              hipStream_t stream){
  const float* x    = (const float*)d_in[0];
  const int*   ei   = (const int*)d_in[1];          // int32 (jax x64 disabled)
  const float* W1   = (const float*)d_in[2];
  const float* as1w = (const float*)d_in[3];
  const float* ad1w = (const float*)d_in[4];
  const float* b1   = (const float*)d_in[5];
  const float* W2   = (const float*)d_in[6];
  const float* as2w = (const float*)d_in[7];
  const float* ad2w = (const float*)d_in[8];
  const float* b2   = (const float*)d_in[9];
  float* out = (float*)d_out;
  const int N = in_sizes[0] / 128;
  const int E = in_sizes[1] / 2;

  char* p = (char*)d_ws;
  auto alloc = [&](size_t bytes) -> void* {
    void* r = (void*)p;
    p += (bytes + 511) & ~(size_t)511;
    return r;
  };
  int*            deg      = (int*)           alloc((size_t)N * 4);
  int*            excl     = (int*)           alloc((size_t)N * 4);
  int*            partials = (int*)           alloc(64 * 4);
  int*            rank     = (int*)           alloc((size_t)E * 4);
  int*            col      = (int*)           alloc((size_t)E * 4);
  float*          a_s1     = (float*)         alloc((size_t)N * 8 * 4);
  float*          a_d1     = (float*)         alloc((size_t)N * 8 * 4);
  unsigned short* out1b    = (unsigned short*)alloc((size_t)N * 128 * 2);
  unsigned short* h1b      = (unsigned short*)alloc((size_t)N * 128 * 2);
  // layer-2 temporaries overlay h1b (dead after agg1): h2b = N*64 ushorts (padded)
  unsigned short* h2b  = h1b;
  float*          a_s2 = (float*)((char*)h1b + (size_t)N * 128);  // right after padded h2b
  float*          a_d2 = a_s2 + N;

  hipMemsetAsync(deg, 0, (size_t)N * 4, stream);

  int gE8 = (E + TB * 8 - 1) / (TB * 8);
  int gE4 = (E + TB * 4 - 1) / (TB * 4);
  int nchunk = (N + SCAN_C - 1) / SCAN_C;

  k_histrank<<<gE8, TB, 0, stream>>>(ei, E, N, deg, rank);
  k_scan1   <<<nchunk, SCAN_T, 0, stream>>>(deg, N, excl, partials);
  k_scan2   <<<1, 64, 0, stream>>>(partials, nchunk);
  k_scan3   <<<(N + TB - 1) / TB, TB, 0, stream>>>(excl, N, partials);
  k_scatter <<<gE4, TB, 0, stream>>>(ei, E, N, excl, rank, col);

  k_gemm1   <<<(N + 127) / 128, 256, 0, stream>>>(x, W1, h1b, N);
  k_att1    <<<(N * 8 + TB - 1) / TB, TB, 0, stream>>>(h1b, as1w, ad1w, a_s1, a_d1, N * 8);
  k_agg1    <<<(N + 3) / 4, 256, 0, stream>>>(h1b, a_s1, a_d1, col, excl, deg, b1, out1b, N);

  k_gemm2   <<<(N + 255) / 256, 256, 0, stream>>>(out1b, W2, h2b, N);
  k_att2    <<<(N + 31) / 32, TB, 0, stream>>>(h2b, as2w, ad2w, a_s2, a_d2, N);
  k_agg2    <<<(N + 3) / 4, 256, 0, stream>>>(h2b, a_s2, a_d2, col, excl, deg, b2, out, N);
}